// Round 6
// baseline (571.320 us; speedup 1.0000x reference)
//
#include <hip/hip_runtime.h>
#include <cstdint>

#define L_SEQ 32400
#define HWSZ  32400
#define MPAD  32512
#define NCH   127
#define DPROJ 524
#define NH    4
#define HD    64
#define NST   4
#define LOG2E 1.4426950408889634f

typedef unsigned short u16;
typedef unsigned int   u32;
typedef __attribute__((ext_vector_type(8))) short short8;
typedef __attribute__((ext_vector_type(4))) float f32x4;

__device__ __forceinline__ float silu_f(float v) {
    float e = __expf(-v);
    return v * __builtin_amdgcn_rcpf(1.f + e);
}
__device__ __forceinline__ float softplus_f(float v) { return v > 20.f ? v : log1pf(__expf(v)); }
__device__ __forceinline__ u16 f2bf(float f) {
    u32 u = __float_as_uint(f);
    u += 0x7FFFu + ((u >> 16) & 1u);
    return (u16)(u >> 16);
}
__device__ __forceinline__ u32 cvtpk(float lo, float hi) {
    u32 r;
    asm("v_cvt_pk_bf16_f32 %0, %1, %2" : "=v"(r) : "v"(lo), "v"(hi));
    return r;
}
__device__ __forceinline__ float bf2f(u32 u) { return __uint_as_float(u << 16); }
__device__ __forceinline__ void gload16(const void* g, void* l) {
    __builtin_amdgcn_global_load_lds(
        (const __attribute__((address_space(1))) u32*)(uintptr_t)g,
        (__attribute__((address_space(3))) u32*)(u32)(uintptr_t)l,
        16, 0, 0);
}

// ---------------------------------------------------------------------------
// Gather + transpose + bf16 pack: xg[inv[pix]][c] = bf16(x[c][pix]).
// ---------------------------------------------------------------------------
__launch_bounds__(256)
__global__ void gather_k(const float* __restrict__ x, const int* __restrict__ inv,
                         u16* __restrict__ xg)
{
    __shared__ u16 tile[256][66];
    const int pix0 = blockIdx.x * 64;
    const int tid = threadIdx.x;
    const int pl = tid & 63, cq = tid >> 6;
    const int pix = pix0 + pl;
    const bool pv = pix < HWSZ;
#pragma unroll 4
    for (int j = 0; j < 64; ++j) {
        int c = cq * 64 + j;
        float v = pv ? x[(size_t)c * HWSZ + pix] : 0.f;
        tile[c][pl] = f2bf(v);
    }
    __syncthreads();
    for (int i = 0; i < 64; ++i) {
        int p2 = pix0 + i;
        if (p2 < HWSZ) {
            int row = inv[p2];
            xg[(size_t)row * 256 + tid] = tile[tid][i];
        }
    }
}

__global__ void zero_k(u16* __restrict__ p, int n)
{
    int i = blockIdx.x * 256 + threadIdx.x;
    if (i < n) p[i] = 0;
}

// Convert f32 [rows][cols] -> bf16 [rowsPad][cols], pad rows zeroed.
__global__ void convpad_k(const float* __restrict__ src, u16* __restrict__ dst,
                          int rows, int cols, int rowsPad)
{
    int r = blockIdx.x;
    for (int c = threadIdx.x; c < cols; c += 256)
        dst[(size_t)r * cols + c] = (r < rows) ? f2bf(src[(size_t)r * cols + c]) : (u16)0;
}

// ---------------------------------------------------------------------------
// bf16 MFMA GEMM, 256x128 tile, BK=64, 8 waves (512 thr).
// MODE 0: plain f32 out (ldo cols). MODE 1: in-proj fused epilogue:
//   col<512  -> zxb bf16 = silu(val)      (z cols 0..255, x cols 256..511)
//   512..519 -> tail f32 = silu(val)      (B, C)
//   520..523 -> tail f32 = val            (dt_raw)
// ---------------------------------------------------------------------------
template<int MODE>
__launch_bounds__(512, 4)
__global__ void gemm2_k(const u16* __restrict__ A, const u16* __restrict__ B,
                        int K, float* __restrict__ outF, int ldo,
                        u16* __restrict__ zxb, float* __restrict__ tail)
{
    __shared__ u16 As[256 * 64];
    __shared__ u16 Bs[128 * 64];
    const int r0 = blockIdx.x * 256, c0 = blockIdx.y * 128;
    const int tid = threadIdx.x;
    const int lane = tid & 63, w = tid >> 6;
    const int wr = (w >> 1) * 64, wc = (w & 1) * 64;
    f32x4 acc[4][4];
#pragma unroll
    for (int m = 0; m < 4; ++m)
#pragma unroll
        for (int n = 0; n < 4; ++n)
            acc[m][n] = (f32x4){0.f, 0.f, 0.f, 0.f};

    const int rlane = lane & 15;
    const int khalf = (lane >> 4) * 16;

    for (int k0 = 0; k0 < K; k0 += 64) {
#pragma unroll
        for (int i = 0; i < 4; ++i) {
            int ch = i * 512 + tid;
            gload16(A + ((size_t)(r0 + (ch >> 3)) * K + k0 + (ch & 7) * 8), (char*)As + ch * 16);
        }
#pragma unroll
        for (int i = 0; i < 2; ++i) {
            int ch = i * 512 + tid;
            gload16(B + ((size_t)(c0 + (ch >> 3)) * K + k0 + (ch & 7) * 8), (char*)Bs + ch * 16);
        }
        __syncthreads();
#pragma unroll
        for (int ks = 0; ks < 2; ++ks) {
            short8 a[4], b[4];
#pragma unroll
            for (int m = 0; m < 4; ++m)
                a[m] = *(const short8*)((const char*)As + (wr + m * 16 + rlane) * 128 + ks * 64 + khalf);
#pragma unroll
            for (int n = 0; n < 4; ++n)
                b[n] = *(const short8*)((const char*)Bs + (wc + n * 16 + rlane) * 128 + ks * 64 + khalf);
#pragma unroll
            for (int m = 0; m < 4; ++m)
#pragma unroll
                for (int n = 0; n < 4; ++n)
                    acc[m][n] = __builtin_amdgcn_mfma_f32_16x16x32_bf16(a[m], b[n], acc[m][n], 0, 0, 0);
        }
        __syncthreads();
    }
    const int rl = (lane >> 4) * 4, cl = lane & 15;
#pragma unroll
    for (int m = 0; m < 4; ++m) {
#pragma unroll
        for (int n = 0; n < 4; ++n) {
            const int col = c0 + wc + n * 16 + cl;
#pragma unroll
            for (int r = 0; r < 4; ++r) {
                const int row = r0 + wr + m * 16 + rl + r;
                if (row >= L_SEQ) continue;
                float v = acc[m][n][r];
                if (MODE == 0) {
                    outF[(size_t)row * ldo + col] = v;
                } else {
                    if (col < 512) {
                        float s = silu_f(v);
                        zxb[(size_t)row * 512 + col] = (u16)cvtpk(s, s);
                    } else if (col < 520) {
                        tail[(size_t)row * 12 + (col - 512)] = silu_f(v);
                    } else if (col < 524) {
                        tail[(size_t)row * 12 + (col - 512)] = v;
                    }
                }
            }
        }
    }
}

// ---------------------------------------------------------------------------
// Per-chunk prep: dt = softplus(dt_raw+bias); acs2 = cumsum(a)*log2e.
// Reads dense 12-col f32 tail.
// ---------------------------------------------------------------------------
__launch_bounds__(256)
__global__ void prep_k(const float* __restrict__ tail, const float* __restrict__ dt_bias,
                       const float* __restrict__ A_log, float* __restrict__ dtb,
                       float* __restrict__ acsb, float* __restrict__ csum)
{
    const int c = blockIdx.x;
    const int l = threadIdx.x;
    const int lane = l & 63, w = l >> 6;
    const int gl = c * 256 + l;
    const bool valid = gl < L_SEQ;
    float v[NH] = {0.f, 0.f, 0.f, 0.f};
    if (valid) {
        float4 dv = *(const float4*)(tail + (size_t)gl * 12 + 8);
        const float* dp = (const float*)&dv;
#pragma unroll
        for (int h = 0; h < NH; ++h) {
            float dt = softplus_f(dp[h] + dt_bias[h]);
            dtb[(size_t)gl * 4 + h] = dt;
            v[h] = -__expf(A_log[h]) * LOG2E * dt;
        }
    }
#pragma unroll
    for (int off = 1; off < 64; off <<= 1) {
#pragma unroll
        for (int h = 0; h < NH; ++h) {
            float t = __shfl_up(v[h], off, 64);
            if (lane >= off) v[h] += t;
        }
    }
    __shared__ float wsum[4][NH];
    if (lane == 63)
#pragma unroll
        for (int h = 0; h < NH; ++h) wsum[w][h] = v[h];
    __syncthreads();
#pragma unroll
    for (int h = 0; h < NH; ++h) {
        float o = 0.f;
#pragma unroll
        for (int w2 = 0; w2 < 4; ++w2) if (w2 < w) o += wsum[w2][h];
        v[h] += o;
    }
    if (valid)
#pragma unroll
        for (int h = 0; h < NH; ++h) acsb[(size_t)gl * 4 + h] = v[h];
    if (l == 255)
#pragma unroll
        for (int h = 0; h < NH; ++h) csum[c * 4 + h] = v[h];
}

// ---------------------------------------------------------------------------
// Chunk-end states, partial; x read as silu'd bf16 from zxb.
// ---------------------------------------------------------------------------
__launch_bounds__(256)
__global__ void states_part_k(const u16* __restrict__ zxb, const float* __restrict__ dtb,
                              const float* __restrict__ tail, const float* __restrict__ acsb,
                              const float* __restrict__ csum, float* __restrict__ spart)
{
    __shared__ float coef[64][16];
    const int c = blockIdx.x, q = blockIdx.y;
    const int tid = threadIdx.x;
    {
        const int l_loc = tid >> 2, h = tid & 3;
        const int gl = c * 256 + q * 64 + l_loc;
        float4 Bv = make_float4(0.f, 0.f, 0.f, 0.f);
        float e = 0.f;
        if (gl < L_SEQ) {
            Bv = *(const float4*)(tail + (size_t)gl * 12);
            e = exp2f(csum[c * 4 + h] - acsb[(size_t)gl * 4 + h]) * dtb[(size_t)gl * 4 + h];
        }
        *(float4*)&coef[l_loc][h * 4] = make_float4(Bv.x * e, Bv.y * e, Bv.z * e, Bv.w * e);
    }
    __syncthreads();
    const int h = tid >> 6;
    f32x4 acc = (f32x4){0.f, 0.f, 0.f, 0.f};
#pragma unroll 4
    for (int j = 0; j < 64; ++j) {
        const int gl = c * 256 + q * 64 + j;
        float xs = 0.f;
        if (gl < L_SEQ) xs = bf2f(zxb[(size_t)gl * 512 + 256 + tid]);
        float4 cf = *(const float4*)&coef[j][h * 4];
        acc[0] += cf.x * xs; acc[1] += cf.y * xs;
        acc[2] += cf.z * xs; acc[3] += cf.w * xs;
    }
    *(f32x4*)(spart + ((size_t)(c * 4 + q) * 256 + tid) * 4) = acc;
}

// ---------------------------------------------------------------------------
// Inter-chunk scan with fused q-reduction (csum2 log2-scaled).
// ---------------------------------------------------------------------------
__launch_bounds__(256)
__global__ void chunkscan_k(const float* __restrict__ csum, const float* __restrict__ spart,
                            float* __restrict__ prev)
{
    const int h = blockIdx.x;
    const int tid = threadIdx.x;
    __shared__ float ecs[NCH];
    if (tid < NCH) ecs[tid] = exp2f(csum[tid * 4 + h]);
    __syncthreads();
    float run = 0.f;
#pragma unroll 2
    for (int c = 0; c < NCH; ++c) {
        const float* sp = spart + (size_t)(c * 4) * 1024 + h * 256 + tid;
        float s = sp[0] + sp[1024] + sp[2048] + sp[3072];
        prev[(size_t)c * 1024 + h * 256 + tid] = run;
        run = run * ecs[c] + s;
    }
}

// ---------------------------------------------------------------------------
// MFMA per-chunk output, v3: 8 waves; prev folded into an extra MFMA k-step;
// pure-copy Xt stage (x already silu'd bf16); slim epilogue (gate = 1 mul).
// ---------------------------------------------------------------------------
__launch_bounds__(512, 6)
__global__ void ychunk3_k(const u16* __restrict__ zxb, const float* __restrict__ tail,
                          const float* __restrict__ dtb, const float* __restrict__ acsb,
                          const float* __restrict__ prev, const float* __restrict__ Dv,
                          const int* __restrict__ mor, u16* __restrict__ cat, int catOff)
{
    __shared__ __align__(16) u16 Xt[64 * 256];   // [p][s] bf16, XOR-swizzled, 32KB
    __shared__ __align__(16) u16 Xp[64 * 40];    // [p][k] prev bf16 (k 0..3 real), 5KB
    __shared__ float4 sBdt[256];
    __shared__ float4 sC[256];
    __shared__ float  sA2[256];

    const int c = blockIdx.x, h = blockIdx.y;
    const int tid = threadIdx.x;
    const int lane = tid & 63, w = tid >> 6;

    // ---- stage X^T (pure copy): wave w -> s in [w*32, w*32+32), p = lane ----
    {
        const int p = lane;
        const size_t colOff = 256 + h * 64 + p;
#pragma unroll
        for (int jq = 0; jq < 4; ++jq) {
            const int s0 = w * 32 + jq * 8;
            u32 wd[4];
#pragma unroll
            for (int q = 0; q < 4; ++q) {
                int gl0 = c * 256 + s0 + q * 2;
                u32 lo = (gl0     < L_SEQ) ? (u32)zxb[(size_t)gl0 * 512 + colOff] : 0u;
                u32 hi = (gl0 + 1 < L_SEQ) ? (u32)zxb[(size_t)(gl0 + 1) * 512 + colOff] : 0u;
                wd[q] = lo | (hi << 16);
            }
            u32 off = (u32)(p * 512 + s0 * 2) ^ (u32)((p & 15) << 4);
            *(uint4*)((char*)Xt + off) = make_uint4(wd[0], wd[1], wd[2], wd[3]);
        }
    }
    // ---- stage prev tile (bf16, k-slots 0..3; rest zero) ----
    if (tid < 64) {
        float4 pv = *(const float4*)(prev + (size_t)c * 1024 + h * 256 + tid * 4);
        u32 w0 = cvtpk(pv.x, pv.y), w1 = cvtpk(pv.z, pv.w);
        uint4* row = (uint4*)((char*)Xp + tid * 80);
        row[0] = make_uint4(w0, w1, 0u, 0u);
        row[1] = make_uint4(0u, 0u, 0u, 0u);
        row[2] = make_uint4(0u, 0u, 0u, 0u);
        row[3] = make_uint4(0u, 0u, 0u, 0u);
    }
    // ---- stage Bdt/C/acs2 ----
    if (tid < 256) {
        const int s = tid, gl = c * 256 + s;
        if (gl < L_SEQ) {
            const float* tr = tail + (size_t)gl * 12;
            float4 B4 = *(const float4*)tr;
            float4 C4v = *(const float4*)(tr + 4);
            float dt = dtb[(size_t)gl * 4 + h];
            sBdt[s] = make_float4(B4.x * dt, B4.y * dt, B4.z * dt, B4.w * dt);
            sC[s] = C4v;
            sA2[s] = acsb[(size_t)gl * 4 + h];
        } else {
            sBdt[s] = make_float4(0.f, 0.f, 0.f, 0.f);
            sC[s] = make_float4(0.f, 0.f, 0.f, 0.f);
            sA2[s] = 0.f;
        }
    }
    __syncthreads();

    const int rl15 = lane & 15, kg = lane >> 4;
    const int R[2] = {w * 16, 240 - w * 16};
    const float Dh = Dv[h];
    int lrow[2]; float4 C4[2]; float al2[2]; int km[2];
#pragma unroll
    for (int m = 0; m < 2; ++m) {
        lrow[m] = R[m] + rl15;
        C4[m] = sC[lrow[m]];
        al2[m] = sA2[lrow[m]];
        km[m] = R[m] >> 5;
    }

    f32x4 acc[2][4];
#pragma unroll
    for (int m = 0; m < 2; ++m)
#pragma unroll
        for (int n = 0; n < 4; ++n)
            acc[m][n] = (f32x4){0.f, 0.f, 0.f, 0.f};

    const int kmW = km[1];   // R[1] >= R[0]
    for (int ks = 0; ks <= kmW; ++ks) {
        const int s0 = ks * 32 + kg * 8;
        short8 bf[4];
#pragma unroll
        for (int n = 0; n < 4; ++n) {
            int col = n * 16 + rl15;
            u32 off = (u32)(col * 512 + ks * 64 + kg * 16) ^ (u32)((col & 15) << 4);
            bf[n] = *(const short8*)((const char*)Xt + off);
        }
        float4 Bv[8]; float a2[8];
#pragma unroll
        for (int j = 0; j < 8; ++j) { Bv[j] = sBdt[s0 + j]; a2[j] = sA2[s0 + j]; }
#pragma unroll
        for (int m = 0; m < 2; ++m) {
            if (ks > km[m]) continue;
            float vv[8];
            if (ks < km[m]) {          // fully below diagonal: no masks
#pragma unroll
                for (int j = 0; j < 8; ++j) {
                    float dot = C4[m].x * Bv[j].x + C4[m].y * Bv[j].y
                              + C4[m].z * Bv[j].z + C4[m].w * Bv[j].w;
                    vv[j] = dot * exp2f(al2[m] - a2[j]);
                }
            } else {                   // diagonal fragment
#pragma unroll
                for (int j = 0; j < 8; ++j) {
                    int s = s0 + j;
                    float dot = C4[m].x * Bv[j].x + C4[m].y * Bv[j].y
                              + C4[m].z * Bv[j].z + C4[m].w * Bv[j].w;
                    float v = dot * exp2f(al2[m] - a2[j]);
                    v = (s <= lrow[m]) ? v : 0.f;
                    vv[j] = (s == lrow[m]) ? v + Dh : v;
                }
            }
            union { u32 wd[4]; short8 v; } aw;
#pragma unroll
            for (int q = 0; q < 4; ++q) aw.wd[q] = cvtpk(vv[2 * q], vv[2 * q + 1]);
#pragma unroll
            for (int n = 0; n < 4; ++n)
                acc[m][n] = __builtin_amdgcn_mfma_f32_16x16x32_bf16(aw.v, bf[n], acc[m][n], 0, 0, 0);
        }
    }
    // ---- prev contribution as one extra MFMA k-step ----
    {
        short8 bp[4];
#pragma unroll
        for (int n = 0; n < 4; ++n) {
            int col = n * 16 + rl15;
            bp[n] = *(const short8*)((const char*)Xp + col * 80 + kg * 16);
        }
#pragma unroll
        for (int m = 0; m < 2; ++m) {
            float ea = exp2f(al2[m]);
            union { u32 wd[4]; short8 v; } aw;
            aw.wd[0] = (kg == 0) ? cvtpk(ea * C4[m].x, ea * C4[m].y) : 0u;
            aw.wd[1] = (kg == 0) ? cvtpk(ea * C4[m].z, ea * C4[m].w) : 0u;
            aw.wd[2] = 0u; aw.wd[3] = 0u;
#pragma unroll
            for (int n = 0; n < 4; ++n)
                acc[m][n] = __builtin_amdgcn_mfma_f32_16x16x32_bf16(aw.v, bp[n], acc[m][n], 0, 0, 0);
        }
    }

    // ---- epilogue: gate with pre-silu'd z, scatter bf16 ----
#pragma unroll
    for (int m = 0; m < 2; ++m) {
#pragma unroll
        for (int r = 0; r < 4; ++r) {
            const int row = R[m] + kg * 4 + r;
            const int gl = c * 256 + row;
            if (gl >= L_SEQ) continue;
            const int pos = mor[gl];
            const size_t zbase = (size_t)gl * 512 + h * 64;
            u16* orow = cat + (size_t)pos * 512 + catOff + h * 64;
#pragma unroll
            for (int n = 0; n < 4; ++n) {
                const int col = n * 16 + rl15;
                float zs = bf2f(zxb[zbase + col]);
                float y = acc[m][n][r] * zs;
                orow[col] = (u16)cvtpk(y, y);
            }
        }
    }
}

// ---------------------------------------------------------------------------
// LayerNorm over channel dim (256).
// ---------------------------------------------------------------------------
__launch_bounds__(256)
__global__ void ln_k(const float* __restrict__ pin, const float* __restrict__ g,
                     const float* __restrict__ b, float* __restrict__ pout)
{
    const int l = blockIdx.x, c = threadIdx.x;
    float v = pin[(size_t)l * 256 + c];
    float s = v, s2 = v * v;
#pragma unroll
    for (int o = 32; o > 0; o >>= 1) { s += __shfl_down(s, o); s2 += __shfl_down(s2, o); }
    __shared__ float ws0[4], ws1[4];
    if ((c & 63) == 0) { ws0[c >> 6] = s; ws1[c >> 6] = s2; }
    __syncthreads();
    float ts = ws0[0] + ws0[1] + ws0[2] + ws0[3];
    float t2 = ws1[0] + ws1[1] + ws1[2] + ws1[3];
    float mu = ts * (1.f / 256.f);
    float var = t2 * (1.f / 256.f) - mu * mu;
    float r = rsqrtf(var + 1e-6f);
    pout[(size_t)l * 256 + c] = (v - mu) * r * g[c] + b[c];
}

// ---------------------------------------------------------------------------
// Transpose (L x 256) -> (256 x L).
// ---------------------------------------------------------------------------
__global__ void transpose_k(const float* __restrict__ pin, float* __restrict__ pout)
{
    __shared__ float t[64][65];
    const int l0 = blockIdx.x * 64, c0 = blockIdx.y * 64;
    const int tx = threadIdx.x, ty = threadIdx.y;
#pragma unroll
    for (int j = 0; j < 16; ++j) {
        int row = ty + j * 4;
        int l = l0 + row;
        t[row][tx] = (l < L_SEQ) ? pin[(size_t)l * 256 + c0 + tx] : 0.f;
    }
    __syncthreads();
#pragma unroll
    for (int j = 0; j < 16; ++j) {
        int crow = ty + j * 4;
        int lcol = l0 + tx;
        if (lcol < L_SEQ) pout[(size_t)(c0 + crow) * L_SEQ + lcol] = t[tx][crow];
    }
}

// ---------------------------------------------------------------------------
extern "C" void kernel_launch(void* const* d_in, const int* in_sizes, int n_in,
                              void* d_out, int out_size, void* d_ws, size_t ws_size,
                              hipStream_t stream)
{
    const float* x        = (const float*)d_in[0];
    const float* W_in[2]  = {(const float*)d_in[1], (const float*)d_in[2]};
    const float* dt_b[2]  = {(const float*)d_in[3], (const float*)d_in[4]};
    const float* A_log[2] = {(const float*)d_in[5], (const float*)d_in[6]};
    const float* Dv[2]    = {(const float*)d_in[7], (const float*)d_in[8]};
    const float* W_out    = (const float*)d_in[9];
    const float* ln_g     = (const float*)d_in[10];
    const float* ln_b     = (const float*)d_in[11];
    const int*   mor[2]   = {(const int*)d_in[12], (const int*)d_in[13]};
    const int*   inv[2]   = {(const int*)d_in[14], (const int*)d_in[15]};

    char* ws = (char*)d_ws;
    size_t off = 0;
    auto alloc = [&](size_t bytes) { char* p = ws + off; off += (bytes + 255) & ~(size_t)255; return p; };
    u16*   zxb  = (u16*)  alloc((size_t)L_SEQ * 512 * 2);   // silu(z)|silu(x); reused as proj f32
    u16*   cat  = (u16*)  alloc((size_t)MPAD * 512 * 2);    // bf16; reused (f32) as LN out
    float* tail = (float*)alloc((size_t)L_SEQ * 12 * 4);    // silu(B)|silu(C)|dt_raw
    u16*   xg   = (u16*)  alloc((size_t)MPAD * 256 * 2);
    u16*   wbuf = (u16*)  alloc((size_t)640 * 256 * 2);
    float* dtb  = (float*)alloc((size_t)L_SEQ * 4 * 4);
    float* acsb = (float*)alloc((size_t)L_SEQ * 4 * 4);
    float* csum = (float*)alloc((size_t)NCH * 4 * 4);
    float* spart= (float*)alloc((size_t)NCH * 4 * 1024 * 4);
    float* prev = (float*)alloc((size_t)NCH * 1024 * 4);
    float* proj  = (float*)zxb;   // zxb dead after both paths' ychunk
    float* lnout = (float*)cat;   // cat dead after out-proj

    for (int path = 0; path < 2; ++path) {
        convpad_k<<<640, 256, 0, stream>>>(W_in[path], wbuf, 524, 256, 640);
        gather_k<<<507, 256, 0, stream>>>(x, inv[path], xg);
        zero_k<<<(112 * 256 + 255) / 256, 256, 0, stream>>>(xg + (size_t)L_SEQ * 256, 112 * 256);
        gemm2_k<1><<<dim3(127, 5), 512, 0, stream>>>(xg, wbuf, 256, nullptr, 0, zxb, tail);
        prep_k<<<NCH, 256, 0, stream>>>(tail, dt_b[path], A_log[path], dtb, acsb, csum);
        states_part_k<<<dim3(NCH, 4), 256, 0, stream>>>(zxb, dtb, tail, acsb, csum, spart);
        chunkscan_k<<<4, 256, 0, stream>>>(csum, spart, prev);
        ychunk3_k<<<dim3(NCH, NH), 512, 0, stream>>>(zxb, tail, dtb, acsb, prev,
                                                     Dv[path], mor[path], cat, path * 256);
    }
    zero_k<<<(112 * 512 + 255) / 256, 256, 0, stream>>>(cat + (size_t)L_SEQ * 512, 112 * 512);
    convpad_k<<<256, 256, 0, stream>>>(W_out, wbuf, 256, 512, 256);
    gemm2_k<0><<<dim3(127, 2), 512, 0, stream>>>(cat, wbuf, 512, proj, 256, nullptr, nullptr);
    ln_k<<<L_SEQ, 256, 0, stream>>>(proj, ln_g, ln_b, lnout);
    transpose_k<<<dim3(507, 4), dim3(64, 4), 0, stream>>>(lnout, (float*)d_out);
}

// Round 7
// 394.697 us; speedup vs baseline: 1.4475x; 1.4475x over previous
//
#include <hip/hip_runtime.h>
#include <cstdint>

#define L_SEQ 32400
#define HWSZ  32400
#define MPAD  32512
#define NCH   127
#define DPROJ 524
#define NH    4
#define HD    64
#define NST   4
#define LOG2E 1.4426950408889634f

typedef unsigned short u16;
typedef unsigned int   u32;
typedef __attribute__((ext_vector_type(8))) short short8;
typedef __attribute__((ext_vector_type(4))) float f32x4;

__device__ __forceinline__ float silu_f(float v) {
    float e = __expf(-v);
    return v * __builtin_amdgcn_rcpf(1.f + e);
}
__device__ __forceinline__ float softplus_f(float v) { return v > 20.f ? v : log1pf(__expf(v)); }
__device__ __forceinline__ u16 f2bf(float f) {
    u32 u = __float_as_uint(f);
    u += 0x7FFFu + ((u >> 16) & 1u);
    return (u16)(u >> 16);
}
__device__ __forceinline__ u32 cvtpk(float lo, float hi) {
    u32 r;
    asm("v_cvt_pk_bf16_f32 %0, %1, %2" : "=v"(r) : "v"(lo), "v"(hi));
    return r;
}
__device__ __forceinline__ float bf2f(u32 u) { return __uint_as_float(u << 16); }
__device__ __forceinline__ void gload16(const void* g, void* l) {
    __builtin_amdgcn_global_load_lds(
        (const __attribute__((address_space(1))) u32*)(uintptr_t)g,
        (__attribute__((address_space(3))) u32*)(u32)(uintptr_t)l,
        16, 0, 0);
}

// ---------------------------------------------------------------------------
// Gather + transpose + bf16 pack: xg[inv[pix]][c] = bf16(x[c][pix]).
// ---------------------------------------------------------------------------
__launch_bounds__(256)
__global__ void gather_k(const float* __restrict__ x, const int* __restrict__ inv,
                         u16* __restrict__ xg)
{
    __shared__ u16 tile[256][66];
    const int pix0 = blockIdx.x * 64;
    const int tid = threadIdx.x;
    const int pl = tid & 63, cq = tid >> 6;
    const int pix = pix0 + pl;
    const bool pv = pix < HWSZ;
#pragma unroll 4
    for (int j = 0; j < 64; ++j) {
        int c = cq * 64 + j;
        float v = pv ? x[(size_t)c * HWSZ + pix] : 0.f;
        tile[c][pl] = f2bf(v);
    }
    __syncthreads();
    for (int i = 0; i < 64; ++i) {
        int p2 = pix0 + i;
        if (p2 < HWSZ) {
            int row = inv[p2];
            xg[(size_t)row * 256 + tid] = tile[tid][i];
        }
    }
}

__global__ void zero_k(u16* __restrict__ p, int n)
{
    int i = blockIdx.x * 256 + threadIdx.x;
    if (i < n) p[i] = 0;
}

// Convert f32 [rows][cols] -> bf16 [rowsPad][cols], pad rows zeroed.
__global__ void convpad_k(const float* __restrict__ src, u16* __restrict__ dst,
                          int rows, int cols, int rowsPad)
{
    int r = blockIdx.x;
    for (int c = threadIdx.x; c < cols; c += 256)
        dst[(size_t)r * cols + c] = (r < rows) ? f2bf(src[(size_t)r * cols + c]) : (u16)0;
}

// ---------------------------------------------------------------------------
// bf16 MFMA GEMM, 256x128 tile, BK=64, 8 waves (512 thr).
// MODE 0: plain f32 out. MODE 1: in-proj fused epilogue (silu + split).
// ---------------------------------------------------------------------------
template<int MODE>
__launch_bounds__(512, 4)
__global__ void gemm2_k(const u16* __restrict__ A, const u16* __restrict__ B,
                        int K, float* __restrict__ outF, int ldo,
                        u16* __restrict__ zxb, float* __restrict__ tail)
{
    __shared__ u16 As[256 * 64];
    __shared__ u16 Bs[128 * 64];
    const int r0 = blockIdx.x * 256, c0 = blockIdx.y * 128;
    const int tid = threadIdx.x;
    const int lane = tid & 63, w = tid >> 6;
    const int wr = (w >> 1) * 64, wc = (w & 1) * 64;
    f32x4 acc[4][4];
#pragma unroll
    for (int m = 0; m < 4; ++m)
#pragma unroll
        for (int n = 0; n < 4; ++n)
            acc[m][n] = (f32x4){0.f, 0.f, 0.f, 0.f};

    const int rlane = lane & 15;
    const int khalf = (lane >> 4) * 16;

    for (int k0 = 0; k0 < K; k0 += 64) {
#pragma unroll
        for (int i = 0; i < 4; ++i) {
            int ch = i * 512 + tid;
            gload16(A + ((size_t)(r0 + (ch >> 3)) * K + k0 + (ch & 7) * 8), (char*)As + ch * 16);
        }
#pragma unroll
        for (int i = 0; i < 2; ++i) {
            int ch = i * 512 + tid;
            gload16(B + ((size_t)(c0 + (ch >> 3)) * K + k0 + (ch & 7) * 8), (char*)Bs + ch * 16);
        }
        __syncthreads();
#pragma unroll
        for (int ks = 0; ks < 2; ++ks) {
            short8 a[4], b[4];
#pragma unroll
            for (int m = 0; m < 4; ++m)
                a[m] = *(const short8*)((const char*)As + (wr + m * 16 + rlane) * 128 + ks * 64 + khalf);
#pragma unroll
            for (int n = 0; n < 4; ++n)
                b[n] = *(const short8*)((const char*)Bs + (wc + n * 16 + rlane) * 128 + ks * 64 + khalf);
#pragma unroll
            for (int m = 0; m < 4; ++m)
#pragma unroll
                for (int n = 0; n < 4; ++n)
                    acc[m][n] = __builtin_amdgcn_mfma_f32_16x16x32_bf16(a[m], b[n], acc[m][n], 0, 0, 0);
        }
        __syncthreads();
    }
    const int rl = (lane >> 4) * 4, cl = lane & 15;
#pragma unroll
    for (int m = 0; m < 4; ++m) {
#pragma unroll
        for (int n = 0; n < 4; ++n) {
            const int col = c0 + wc + n * 16 + cl;
#pragma unroll
            for (int r = 0; r < 4; ++r) {
                const int row = r0 + wr + m * 16 + rl + r;
                if (row >= L_SEQ) continue;
                float v = acc[m][n][r];
                if (MODE == 0) {
                    outF[(size_t)row * ldo + col] = v;
                } else {
                    if (col < 512) {
                        float s = silu_f(v);
                        zxb[(size_t)row * 512 + col] = (u16)cvtpk(s, s);
                    } else if (col < 520) {
                        tail[(size_t)row * 12 + (col - 512)] = silu_f(v);
                    } else if (col < 524) {
                        tail[(size_t)row * 12 + (col - 512)] = v;
                    }
                }
            }
        }
    }
}

// ---------------------------------------------------------------------------
// Per-chunk prep: dt = softplus(dt_raw+bias); acs2 = cumsum(a)*log2e.
// ---------------------------------------------------------------------------
__launch_bounds__(256)
__global__ void prep_k(const float* __restrict__ tail, const float* __restrict__ dt_bias,
                       const float* __restrict__ A_log, float* __restrict__ dtb,
                       float* __restrict__ acsb, float* __restrict__ csum)
{
    const int c = blockIdx.x;
    const int l = threadIdx.x;
    const int lane = l & 63, w = l >> 6;
    const int gl = c * 256 + l;
    const bool valid = gl < L_SEQ;
    float v[NH] = {0.f, 0.f, 0.f, 0.f};
    if (valid) {
        float4 dv = *(const float4*)(tail + (size_t)gl * 12 + 8);
        const float* dp = (const float*)&dv;
#pragma unroll
        for (int h = 0; h < NH; ++h) {
            float dt = softplus_f(dp[h] + dt_bias[h]);
            dtb[(size_t)gl * 4 + h] = dt;
            v[h] = -__expf(A_log[h]) * LOG2E * dt;
        }
    }
#pragma unroll
    for (int off = 1; off < 64; off <<= 1) {
#pragma unroll
        for (int h = 0; h < NH; ++h) {
            float t = __shfl_up(v[h], off, 64);
            if (lane >= off) v[h] += t;
        }
    }
    __shared__ float wsum[4][NH];
    if (lane == 63)
#pragma unroll
        for (int h = 0; h < NH; ++h) wsum[w][h] = v[h];
    __syncthreads();
#pragma unroll
    for (int h = 0; h < NH; ++h) {
        float o = 0.f;
#pragma unroll
        for (int w2 = 0; w2 < 4; ++w2) if (w2 < w) o += wsum[w2][h];
        v[h] += o;
    }
    if (valid)
#pragma unroll
        for (int h = 0; h < NH; ++h) acsb[(size_t)gl * 4 + h] = v[h];
    if (l == 255)
#pragma unroll
        for (int h = 0; h < NH; ++h) csum[c * 4 + h] = v[h];
}

// ---------------------------------------------------------------------------
// Chunk-end states, partial; x read as silu'd bf16 from zxb.
// ---------------------------------------------------------------------------
__launch_bounds__(256)
__global__ void states_part_k(const u16* __restrict__ zxb, const float* __restrict__ dtb,
                              const float* __restrict__ tail, const float* __restrict__ acsb,
                              const float* __restrict__ csum, float* __restrict__ spart)
{
    __shared__ float coef[64][16];
    const int c = blockIdx.x, q = blockIdx.y;
    const int tid = threadIdx.x;
    {
        const int l_loc = tid >> 2, h = tid & 3;
        const int gl = c * 256 + q * 64 + l_loc;
        float4 Bv = make_float4(0.f, 0.f, 0.f, 0.f);
        float e = 0.f;
        if (gl < L_SEQ) {
            Bv = *(const float4*)(tail + (size_t)gl * 12);
            e = exp2f(csum[c * 4 + h] - acsb[(size_t)gl * 4 + h]) * dtb[(size_t)gl * 4 + h];
        }
        *(float4*)&coef[l_loc][h * 4] = make_float4(Bv.x * e, Bv.y * e, Bv.z * e, Bv.w * e);
    }
    __syncthreads();
    const int h = tid >> 6;
    f32x4 acc = (f32x4){0.f, 0.f, 0.f, 0.f};
#pragma unroll 4
    for (int j = 0; j < 64; ++j) {
        const int gl = c * 256 + q * 64 + j;
        float xs = 0.f;
        if (gl < L_SEQ) xs = bf2f(zxb[(size_t)gl * 512 + 256 + tid]);
        float4 cf = *(const float4*)&coef[j][h * 4];
        acc[0] += cf.x * xs; acc[1] += cf.y * xs;
        acc[2] += cf.z * xs; acc[3] += cf.w * xs;
    }
    *(f32x4*)(spart + ((size_t)(c * 4 + q) * 256 + tid) * 4) = acc;
}

// ---------------------------------------------------------------------------
// Inter-chunk scan with fused q-reduction (csum2 log2-scaled).
// ---------------------------------------------------------------------------
__launch_bounds__(256)
__global__ void chunkscan_k(const float* __restrict__ csum, const float* __restrict__ spart,
                            float* __restrict__ prev)
{
    const int h = blockIdx.x;
    const int tid = threadIdx.x;
    __shared__ float ecs[NCH];
    if (tid < NCH) ecs[tid] = exp2f(csum[tid * 4 + h]);
    __syncthreads();
    float run = 0.f;
#pragma unroll 2
    for (int c = 0; c < NCH; ++c) {
        const float* sp = spart + (size_t)(c * 4) * 1024 + h * 256 + tid;
        float s = sp[0] + sp[1024] + sp[2048] + sp[3072];
        prev[(size_t)c * 1024 + h * 256 + tid] = run;
        run = run * ecs[c] + s;
    }
}

// ---------------------------------------------------------------------------
// MFMA per-chunk output, v3 (spill-fixed): 8 waves, prev folded into MFMA,
// pure-copy Xt stage, slim epilogue.  launch_bounds(512,2): VGPR cap 256.
// ---------------------------------------------------------------------------
__launch_bounds__(512, 2)
__global__ void ychunk3_k(const u16* __restrict__ zxb, const float* __restrict__ tail,
                          const float* __restrict__ dtb, const float* __restrict__ acsb,
                          const float* __restrict__ prev, const float* __restrict__ Dv,
                          const int* __restrict__ mor, u16* __restrict__ cat, int catOff)
{
    __shared__ __align__(16) u16 Xt[64 * 256];   // [p][s] bf16, XOR-swizzled, 32KB
    __shared__ __align__(16) u16 Xp[64 * 40];    // [p][k] prev bf16 (k 0..3 real), 5KB
    __shared__ float4 sBdt[256];
    __shared__ float4 sC[256];
    __shared__ float  sA2[256];

    const int c = blockIdx.x, h = blockIdx.y;
    const int tid = threadIdx.x;
    const int lane = tid & 63, w = tid >> 6;

    // ---- stage X^T (pure copy): wave w -> s in [w*32, w*32+32), p = lane ----
    {
        const int p = lane;
        const size_t colOff = 256 + h * 64 + p;
#pragma unroll
        for (int jq = 0; jq < 4; ++jq) {
            const int s0 = w * 32 + jq * 8;
            u32 wd[4];
#pragma unroll
            for (int q = 0; q < 4; ++q) {
                int gl0 = c * 256 + s0 + q * 2;
                u32 lo = (gl0     < L_SEQ) ? (u32)zxb[(size_t)gl0 * 512 + colOff] : 0u;
                u32 hi = (gl0 + 1 < L_SEQ) ? (u32)zxb[(size_t)(gl0 + 1) * 512 + colOff] : 0u;
                wd[q] = lo | (hi << 16);
            }
            u32 off = (u32)(p * 512 + s0 * 2) ^ (u32)((p & 15) << 4);
            *(uint4*)((char*)Xt + off) = make_uint4(wd[0], wd[1], wd[2], wd[3]);
        }
    }
    // ---- stage prev tile (bf16, k-slots 0..3; rest zero) ----
    if (tid < 64) {
        float4 pv = *(const float4*)(prev + (size_t)c * 1024 + h * 256 + tid * 4);
        u32 w0 = cvtpk(pv.x, pv.y), w1 = cvtpk(pv.z, pv.w);
        uint4* row = (uint4*)((char*)Xp + tid * 80);
        row[0] = make_uint4(w0, w1, 0u, 0u);
        row[1] = make_uint4(0u, 0u, 0u, 0u);
        row[2] = make_uint4(0u, 0u, 0u, 0u);
        row[3] = make_uint4(0u, 0u, 0u, 0u);
    }
    // ---- stage Bdt/C/acs2 ----
    if (tid < 256) {
        const int s = tid, gl = c * 256 + s;
        if (gl < L_SEQ) {
            const float* tr = tail + (size_t)gl * 12;
            float4 B4 = *(const float4*)tr;
            float4 C4v = *(const float4*)(tr + 4);
            float dt = dtb[(size_t)gl * 4 + h];
            sBdt[s] = make_float4(B4.x * dt, B4.y * dt, B4.z * dt, B4.w * dt);
            sC[s] = C4v;
            sA2[s] = acsb[(size_t)gl * 4 + h];
        } else {
            sBdt[s] = make_float4(0.f, 0.f, 0.f, 0.f);
            sC[s] = make_float4(0.f, 0.f, 0.f, 0.f);
            sA2[s] = 0.f;
        }
    }
    __syncthreads();

    const int rl15 = lane & 15, kg = lane >> 4;
    const int R[2] = {w * 16, 240 - w * 16};
    const float Dh = Dv[h];
    int lrow[2]; float4 C4[2]; float al2[2]; int km[2];
#pragma unroll
    for (int m = 0; m < 2; ++m) {
        lrow[m] = R[m] + rl15;
        C4[m] = sC[lrow[m]];
        al2[m] = sA2[lrow[m]];
        km[m] = R[m] >> 5;
    }

    f32x4 acc[2][4];
#pragma unroll
    for (int m = 0; m < 2; ++m)
#pragma unroll
        for (int n = 0; n < 4; ++n)
            acc[m][n] = (f32x4){0.f, 0.f, 0.f, 0.f};

    const int kmW = km[1];   // R[1] >= R[0]
    for (int ks = 0; ks <= kmW; ++ks) {
        const int s0 = ks * 32 + kg * 8;
        short8 bf[4];
#pragma unroll
        for (int n = 0; n < 4; ++n) {
            int col = n * 16 + rl15;
            u32 off = (u32)(col * 512 + ks * 64 + kg * 16) ^ (u32)((col & 15) << 4);
            bf[n] = *(const short8*)((const char*)Xt + off);
        }
        float4 Bv[8]; float a2[8];
#pragma unroll
        for (int j = 0; j < 8; ++j) { Bv[j] = sBdt[s0 + j]; a2[j] = sA2[s0 + j]; }
#pragma unroll
        for (int m = 0; m < 2; ++m) {
            if (ks > km[m]) continue;
            float vv[8];
            if (ks < km[m]) {          // fully below diagonal: no masks
#pragma unroll
                for (int j = 0; j < 8; ++j) {
                    float dot = C4[m].x * Bv[j].x + C4[m].y * Bv[j].y
                              + C4[m].z * Bv[j].z + C4[m].w * Bv[j].w;
                    vv[j] = dot * exp2f(al2[m] - a2[j]);
                }
            } else {                   // diagonal fragment
#pragma unroll
                for (int j = 0; j < 8; ++j) {
                    int s = s0 + j;
                    float dot = C4[m].x * Bv[j].x + C4[m].y * Bv[j].y
                              + C4[m].z * Bv[j].z + C4[m].w * Bv[j].w;
                    float v = dot * exp2f(al2[m] - a2[j]);
                    v = (s <= lrow[m]) ? v : 0.f;
                    vv[j] = (s == lrow[m]) ? v + Dh : v;
                }
            }
            union { u32 wd[4]; short8 v; } aw;
#pragma unroll
            for (int q = 0; q < 4; ++q) aw.wd[q] = cvtpk(vv[2 * q], vv[2 * q + 1]);
#pragma unroll
            for (int n = 0; n < 4; ++n)
                acc[m][n] = __builtin_amdgcn_mfma_f32_16x16x32_bf16(aw.v, bf[n], acc[m][n], 0, 0, 0);
        }
    }
    // ---- prev contribution as one extra MFMA k-step ----
    {
        short8 bp[4];
#pragma unroll
        for (int n = 0; n < 4; ++n) {
            int col = n * 16 + rl15;
            bp[n] = *(const short8*)((const char*)Xp + col * 80 + kg * 16);
        }
#pragma unroll
        for (int m = 0; m < 2; ++m) {
            float ea = exp2f(al2[m]);
            union { u32 wd[4]; short8 v; } aw;
            aw.wd[0] = (kg == 0) ? cvtpk(ea * C4[m].x, ea * C4[m].y) : 0u;
            aw.wd[1] = (kg == 0) ? cvtpk(ea * C4[m].z, ea * C4[m].w) : 0u;
            aw.wd[2] = 0u; aw.wd[3] = 0u;
#pragma unroll
            for (int n = 0; n < 4; ++n)
                acc[m][n] = __builtin_amdgcn_mfma_f32_16x16x32_bf16(aw.v, bp[n], acc[m][n], 0, 0, 0);
        }
    }

    // ---- epilogue: gate with pre-silu'd z, scatter bf16 ----
#pragma unroll
    for (int m = 0; m < 2; ++m) {
#pragma unroll
        for (int r = 0; r < 4; ++r) {
            const int row = R[m] + kg * 4 + r;
            const int gl = c * 256 + row;
            if (gl >= L_SEQ) continue;
            const int pos = mor[gl];
            const size_t zbase = (size_t)gl * 512 + h * 64;
            u16* orow = cat + (size_t)pos * 512 + catOff + h * 64;
#pragma unroll
            for (int n = 0; n < 4; ++n) {
                const int col = n * 16 + rl15;
                float zs = bf2f(zxb[zbase + col]);
                float y = acc[m][n][r] * zs;
                orow[col] = (u16)cvtpk(y, y);
            }
        }
    }
}

// ---------------------------------------------------------------------------
// LayerNorm over channel dim (256).
// ---------------------------------------------------------------------------
__launch_bounds__(256)
__global__ void ln_k(const float* __restrict__ pin, const float* __restrict__ g,
                     const float* __restrict__ b, float* __restrict__ pout)
{
    const int l = blockIdx.x, c = threadIdx.x;
    float v = pin[(size_t)l * 256 + c];
    float s = v, s2 = v * v;
#pragma unroll
    for (int o = 32; o > 0; o >>= 1) { s += __shfl_down(s, o); s2 += __shfl_down(s2, o); }
    __shared__ float ws0[4], ws1[4];
    if ((c & 63) == 0) { ws0[c >> 6] = s; ws1[c >> 6] = s2; }
    __syncthreads();
    float ts = ws0[0] + ws0[1] + ws0[2] + ws0[3];
    float t2 = ws1[0] + ws1[1] + ws1[2] + ws1[3];
    float mu = ts * (1.f / 256.f);
    float var = t2 * (1.f / 256.f) - mu * mu;
    float r = rsqrtf(var + 1e-6f);
    pout[(size_t)l * 256 + c] = (v - mu) * r * g[c] + b[c];
}

// ---------------------------------------------------------------------------
// Transpose (L x 256) -> (256 x L).
// ---------------------------------------------------------------------------
__global__ void transpose_k(const float* __restrict__ pin, float* __restrict__ pout)
{
    __shared__ float t[64][65];
    const int l0 = blockIdx.x * 64, c0 = blockIdx.y * 64;
    const int tx = threadIdx.x, ty = threadIdx.y;
#pragma unroll
    for (int j = 0; j < 16; ++j) {
        int row = ty + j * 4;
        int l = l0 + row;
        t[row][tx] = (l < L_SEQ) ? pin[(size_t)l * 256 + c0 + tx] : 0.f;
    }
    __syncthreads();
#pragma unroll
    for (int j = 0; j < 16; ++j) {
        int crow = ty + j * 4;
        int lcol = l0 + tx;
        if (lcol < L_SEQ) pout[(size_t)(c0 + crow) * L_SEQ + lcol] = t[tx][crow];
    }
}

// ---------------------------------------------------------------------------
extern "C" void kernel_launch(void* const* d_in, const int* in_sizes, int n_in,
                              void* d_out, int out_size, void* d_ws, size_t ws_size,
                              hipStream_t stream)
{
    const float* x        = (const float*)d_in[0];
    const float* W_in[2]  = {(const float*)d_in[1], (const float*)d_in[2]};
    const float* dt_b[2]  = {(const float*)d_in[3], (const float*)d_in[4]};
    const float* A_log[2] = {(const float*)d_in[5], (const float*)d_in[6]};
    const float* Dv[2]    = {(const float*)d_in[7], (const float*)d_in[8]};
    const float* W_out    = (const float*)d_in[9];
    const float* ln_g     = (const float*)d_in[10];
    const float* ln_b     = (const float*)d_in[11];
    const int*   mor[2]   = {(const int*)d_in[12], (const int*)d_in[13]};
    const int*   inv[2]   = {(const int*)d_in[14], (const int*)d_in[15]};

    char* ws = (char*)d_ws;
    size_t off = 0;
    auto alloc = [&](size_t bytes) { char* p = ws + off; off += (bytes + 255) & ~(size_t)255; return p; };
    u16*   zxb  = (u16*)  alloc((size_t)L_SEQ * 512 * 2);   // silu(z)|silu(x); reused as proj f32
    u16*   cat  = (u16*)  alloc((size_t)MPAD * 512 * 2);    // bf16; reused (f32) as LN out
    float* tail = (float*)alloc((size_t)L_SEQ * 12 * 4);    // silu(B)|silu(C)|dt_raw
    u16*   xg   = (u16*)  alloc((size_t)MPAD * 256 * 2);
    u16*   wbuf = (u16*)  alloc((size_t)640 * 256 * 2);
    float* dtb  = (float*)alloc((size_t)L_SEQ * 4 * 4);
    float* acsb = (float*)alloc((size_t)L_SEQ * 4 * 4);
    float* csum = (float*)alloc((size_t)NCH * 4 * 4);
    float* spart= (float*)alloc((size_t)NCH * 4 * 1024 * 4);
    float* prev = (float*)alloc((size_t)NCH * 1024 * 4);
    float* proj  = (float*)zxb;   // zxb dead after both paths' ychunk
    float* lnout = (float*)cat;   // cat dead after out-proj

    for (int path = 0; path < 2; ++path) {
        convpad_k<<<640, 256, 0, stream>>>(W_in[path], wbuf, 524, 256, 640);
        gather_k<<<507, 256, 0, stream>>>(x, inv[path], xg);
        zero_k<<<(112 * 256 + 255) / 256, 256, 0, stream>>>(xg + (size_t)L_SEQ * 256, 112 * 256);
        gemm2_k<1><<<dim3(127, 5), 512, 0, stream>>>(xg, wbuf, 256, nullptr, 0, zxb, tail);
        prep_k<<<NCH, 256, 0, stream>>>(tail, dt_b[path], A_log[path], dtb, acsb, csum);
        states_part_k<<<dim3(NCH, 4), 256, 0, stream>>>(zxb, dtb, tail, acsb, csum, spart);
        chunkscan_k<<<4, 256, 0, stream>>>(csum, spart, prev);
        ychunk3_k<<<dim3(NCH, NH), 512, 0, stream>>>(zxb, tail, dtb, acsb, prev,
                                                     Dv[path], mor[path], cat, path * 256);
    }
    zero_k<<<(112 * 512 + 255) / 256, 256, 0, stream>>>(cat + (size_t)L_SEQ * 512, 112 * 512);
    convpad_k<<<256, 256, 0, stream>>>(W_out, wbuf, 256, 512, 256);
    gemm2_k<0><<<dim3(127, 2), 512, 0, stream>>>(cat, wbuf, 512, proj, 256, nullptr, nullptr);
    ln_k<<<L_SEQ, 256, 0, stream>>>(proj, ln_g, ln_b, lnout);
    transpose_k<<<dim3(507, 4), dim3(64, 4), 0, stream>>>(lnout, (float*)d_out);
}

// Round 8
// 382.963 us; speedup vs baseline: 1.4918x; 1.0306x over previous
//
#include <hip/hip_runtime.h>
#include <cstdint>

#define L_SEQ 32400
#define HWSZ  32400
#define MPAD  32512
#define NCH   127
#define DPROJ 524
#define NH    4
#define HD    64
#define NST   4
#define LOG2E 1.4426950408889634f

typedef unsigned short u16;
typedef unsigned int   u32;
typedef __attribute__((ext_vector_type(8))) short short8;
typedef __attribute__((ext_vector_type(4))) float f32x4;

__device__ __forceinline__ float silu_f(float v) {
    float e = __expf(-v);
    return v * __builtin_amdgcn_rcpf(1.f + e);
}
__device__ __forceinline__ float softplus_f(float v) { return v > 20.f ? v : log1pf(__expf(v)); }
__device__ __forceinline__ u16 f2bf(float f) {
    u32 u = __float_as_uint(f);
    u += 0x7FFFu + ((u >> 16) & 1u);
    return (u16)(u >> 16);
}
__device__ __forceinline__ u32 cvtpk(float lo, float hi) {
    u32 r;
    asm("v_cvt_pk_bf16_f32 %0, %1, %2" : "=v"(r) : "v"(lo), "v"(hi));
    return r;
}
__device__ __forceinline__ float bf2f(u32 u) { return __uint_as_float(u << 16); }
__device__ __forceinline__ void gload16(const void* g, void* l) {
    __builtin_amdgcn_global_load_lds(
        (const __attribute__((address_space(1))) u32*)(uintptr_t)g,
        (__attribute__((address_space(3))) u32*)(u32)(uintptr_t)l,
        16, 0, 0);
}

// ---------------------------------------------------------------------------
// Gather + transpose + bf16 pack: xg[inv[pix]][c] = bf16(x[c][pix]).
// ---------------------------------------------------------------------------
__launch_bounds__(256)
__global__ void gather_k(const float* __restrict__ x, const int* __restrict__ inv,
                         u16* __restrict__ xg)
{
    __shared__ u16 tile[256][66];
    const int pix0 = blockIdx.x * 64;
    const int tid = threadIdx.x;
    const int pl = tid & 63, cq = tid >> 6;
    const int pix = pix0 + pl;
    const bool pv = pix < HWSZ;
#pragma unroll 4
    for (int j = 0; j < 64; ++j) {
        int c = cq * 64 + j;
        float v = pv ? x[(size_t)c * HWSZ + pix] : 0.f;
        tile[c][pl] = f2bf(v);
    }
    __syncthreads();
    for (int i = 0; i < 64; ++i) {
        int p2 = pix0 + i;
        if (p2 < HWSZ) {
            int row = inv[p2];
            xg[(size_t)row * 256 + tid] = tile[tid][i];
        }
    }
}

__global__ void zero_k(u16* __restrict__ p, int n)
{
    int i = blockIdx.x * 256 + threadIdx.x;
    if (i < n) p[i] = 0;
}

// Convert f32 [rows][cols] -> bf16 [rowsPad][cols], pad rows zeroed.
__global__ void convpad_k(const float* __restrict__ src, u16* __restrict__ dst,
                          int rows, int cols, int rowsPad)
{
    int r = blockIdx.x;
    for (int c = threadIdx.x; c < cols; c += 256)
        dst[(size_t)r * cols + c] = (r < rows) ? f2bf(src[(size_t)r * cols + c]) : (u16)0;
}

// ---------------------------------------------------------------------------
// bf16 MFMA GEMM v3: 128x128 tile, BK=64, 4 waves, double-buffered LDS with
// counted vmcnt (2-phase pipeline), XOR-swizzled LDS via pre-swizzled source.
// Grid: (ncolblocks, nrowblocks) -> consecutive blocks share the A row-panel.
// MODE 0: plain f32 out. MODE 1: in-proj fused epilogue (silu + split).
// ---------------------------------------------------------------------------
template<int MODE>
__launch_bounds__(256, 2)
__global__ void gemm2_k(const u16* __restrict__ A, const u16* __restrict__ B,
                        int K, float* __restrict__ outF, int ldo,
                        u16* __restrict__ zxb, float* __restrict__ tail)
{
    __shared__ u16 As[2][128 * 64];
    __shared__ u16 Bs[2][128 * 64];
    const int c0 = blockIdx.x * 128, r0 = blockIdx.y * 128;
    const int tid = threadIdx.x;
    const int lane = tid & 63, w = tid >> 6;
    const int wr = (w >> 1) * 64, wc = (w & 1) * 64;
    const int rlane = lane & 15, kg = lane >> 4;

    f32x4 acc[4][4];
#pragma unroll
    for (int m = 0; m < 4; ++m)
#pragma unroll
        for (int n = 0; n < 4; ++n)
            acc[m][n] = (f32x4){0.f, 0.f, 0.f, 0.f};

    // stage one 128x64 A-tile + B-tile into buf; source k-slot pre-swizzled
    // (slot ^ (row&7)) so that swizzled reads land conflict-free (rule #21).
    auto stage = [&](int k0, int buf) {
#pragma unroll
        for (int i = 0; i < 4; ++i) {
            int ch = i * 256 + tid;
            int row = ch >> 3, slot = ch & 7;
            int ksw = slot ^ (row & 7);
            gload16(A + (size_t)(r0 + row) * K + k0 + ksw * 8, (char*)As[buf] + ch * 16);
        }
#pragma unroll
        for (int i = 0; i < 4; ++i) {
            int ch = i * 256 + tid;
            int row = ch >> 3, slot = ch & 7;
            int ksw = slot ^ (row & 7);
            gload16(B + (size_t)(c0 + row) * K + k0 + ksw * 8, (char*)Bs[buf] + ch * 16);
        }
    };

    const int nk = K >> 6;
    stage(0, 0);
    int cur = 0;
    for (int t = 0; t < nk; ++t) {
        if (t + 1 < nk) {
            stage((t + 1) * 64, cur ^ 1);
            asm volatile("s_waitcnt vmcnt(8)" ::: "memory");   // cur's 8 loads done
        } else {
            asm volatile("s_waitcnt vmcnt(0)" ::: "memory");
        }
        __builtin_amdgcn_s_barrier();
        __builtin_amdgcn_sched_barrier(0);
        const char* Ab = (const char*)&As[cur][0];
        const char* Bb = (const char*)&Bs[cur][0];
#pragma unroll
        for (int ks = 0; ks < 2; ++ks) {
            short8 a[4], b[4];
#pragma unroll
            for (int m = 0; m < 4; ++m) {
                int row = wr + m * 16 + rlane;
                int sw = (ks * 4 + kg) ^ (row & 7);
                a[m] = *(const short8*)(Ab + row * 128 + sw * 16);
            }
#pragma unroll
            for (int n = 0; n < 4; ++n) {
                int row = wc + n * 16 + rlane;
                int sw = (ks * 4 + kg) ^ (row & 7);
                b[n] = *(const short8*)(Bb + row * 128 + sw * 16);
            }
            __builtin_amdgcn_s_setprio(1);
#pragma unroll
            for (int m = 0; m < 4; ++m)
#pragma unroll
                for (int n = 0; n < 4; ++n)
                    acc[m][n] = __builtin_amdgcn_mfma_f32_16x16x32_bf16(a[m], b[n], acc[m][n], 0, 0, 0);
            __builtin_amdgcn_s_setprio(0);
        }
        __builtin_amdgcn_sched_barrier(0);
        __builtin_amdgcn_s_barrier();
        cur ^= 1;
    }

    const int rl = (lane >> 4) * 4, cl = lane & 15;
#pragma unroll
    for (int m = 0; m < 4; ++m) {
#pragma unroll
        for (int n = 0; n < 4; ++n) {
            const int col = c0 + wc + n * 16 + cl;
#pragma unroll
            for (int r = 0; r < 4; ++r) {
                const int row = r0 + wr + m * 16 + rl + r;
                if (row >= L_SEQ) continue;
                float v = acc[m][n][r];
                if (MODE == 0) {
                    outF[(size_t)row * ldo + col] = v;
                } else {
                    if (col < 512) {
                        float s = silu_f(v);
                        zxb[(size_t)row * 512 + col] = (u16)cvtpk(s, s);
                    } else if (col < 520) {
                        tail[(size_t)row * 12 + (col - 512)] = silu_f(v);
                    } else if (col < 524) {
                        tail[(size_t)row * 12 + (col - 512)] = v;
                    }
                }
            }
        }
    }
}

// ---------------------------------------------------------------------------
// Per-chunk prep: dt = softplus(dt_raw+bias); acs2 = cumsum(a)*log2e.
// ---------------------------------------------------------------------------
__launch_bounds__(256)
__global__ void prep_k(const float* __restrict__ tail, const float* __restrict__ dt_bias,
                       const float* __restrict__ A_log, float* __restrict__ dtb,
                       float* __restrict__ acsb, float* __restrict__ csum)
{
    const int c = blockIdx.x;
    const int l = threadIdx.x;
    const int lane = l & 63, w = l >> 6;
    const int gl = c * 256 + l;
    const bool valid = gl < L_SEQ;
    float v[NH] = {0.f, 0.f, 0.f, 0.f};
    if (valid) {
        float4 dv = *(const float4*)(tail + (size_t)gl * 12 + 8);
        const float* dp = (const float*)&dv;
#pragma unroll
        for (int h = 0; h < NH; ++h) {
            float dt = softplus_f(dp[h] + dt_bias[h]);
            dtb[(size_t)gl * 4 + h] = dt;
            v[h] = -__expf(A_log[h]) * LOG2E * dt;
        }
    }
#pragma unroll
    for (int off = 1; off < 64; off <<= 1) {
#pragma unroll
        for (int h = 0; h < NH; ++h) {
            float t = __shfl_up(v[h], off, 64);
            if (lane >= off) v[h] += t;
        }
    }
    __shared__ float wsum[4][NH];
    if (lane == 63)
#pragma unroll
        for (int h = 0; h < NH; ++h) wsum[w][h] = v[h];
    __syncthreads();
#pragma unroll
    for (int h = 0; h < NH; ++h) {
        float o = 0.f;
#pragma unroll
        for (int w2 = 0; w2 < 4; ++w2) if (w2 < w) o += wsum[w2][h];
        v[h] += o;
    }
    if (valid)
#pragma unroll
        for (int h = 0; h < NH; ++h) acsb[(size_t)gl * 4 + h] = v[h];
    if (l == 255)
#pragma unroll
        for (int h = 0; h < NH; ++h) csum[c * 4 + h] = v[h];
}

// ---------------------------------------------------------------------------
// Chunk-end states, partial; x read as silu'd bf16 from zxb.
// ---------------------------------------------------------------------------
__launch_bounds__(256)
__global__ void states_part_k(const u16* __restrict__ zxb, const float* __restrict__ dtb,
                              const float* __restrict__ tail, const float* __restrict__ acsb,
                              const float* __restrict__ csum, float* __restrict__ spart)
{
    __shared__ float coef[64][16];
    const int c = blockIdx.x, q = blockIdx.y;
    const int tid = threadIdx.x;
    {
        const int l_loc = tid >> 2, h = tid & 3;
        const int gl = c * 256 + q * 64 + l_loc;
        float4 Bv = make_float4(0.f, 0.f, 0.f, 0.f);
        float e = 0.f;
        if (gl < L_SEQ) {
            Bv = *(const float4*)(tail + (size_t)gl * 12);
            e = exp2f(csum[c * 4 + h] - acsb[(size_t)gl * 4 + h]) * dtb[(size_t)gl * 4 + h];
        }
        *(float4*)&coef[l_loc][h * 4] = make_float4(Bv.x * e, Bv.y * e, Bv.z * e, Bv.w * e);
    }
    __syncthreads();
    const int h = tid >> 6;
    f32x4 acc = (f32x4){0.f, 0.f, 0.f, 0.f};
#pragma unroll 4
    for (int j = 0; j < 64; ++j) {
        const int gl = c * 256 + q * 64 + j;
        float xs = 0.f;
        if (gl < L_SEQ) xs = bf2f(zxb[(size_t)gl * 512 + 256 + tid]);
        float4 cf = *(const float4*)&coef[j][h * 4];
        acc[0] += cf.x * xs; acc[1] += cf.y * xs;
        acc[2] += cf.z * xs; acc[3] += cf.w * xs;
    }
    *(f32x4*)(spart + ((size_t)(c * 4 + q) * 256 + tid) * 4) = acc;
}

// ---------------------------------------------------------------------------
// Inter-chunk scan with fused q-reduction (csum2 log2-scaled).
// ---------------------------------------------------------------------------
__launch_bounds__(256)
__global__ void chunkscan_k(const float* __restrict__ csum, const float* __restrict__ spart,
                            float* __restrict__ prev)
{
    const int h = blockIdx.x;
    const int tid = threadIdx.x;
    __shared__ float ecs[NCH];
    if (tid < NCH) ecs[tid] = exp2f(csum[tid * 4 + h]);
    __syncthreads();
    float run = 0.f;
#pragma unroll 2
    for (int c = 0; c < NCH; ++c) {
        const float* sp = spart + (size_t)(c * 4) * 1024 + h * 256 + tid;
        float s = sp[0] + sp[1024] + sp[2048] + sp[3072];
        prev[(size_t)c * 1024 + h * 256 + tid] = run;
        run = run * ecs[c] + s;
    }
}

// ---------------------------------------------------------------------------
// MFMA per-chunk output, v3: 8 waves, prev folded into MFMA, pure-copy Xt
// stage, slim epilogue.  launch_bounds(512,2): VGPR cap 256.
// ---------------------------------------------------------------------------
__launch_bounds__(512, 2)
__global__ void ychunk3_k(const u16* __restrict__ zxb, const float* __restrict__ tail,
                          const float* __restrict__ dtb, const float* __restrict__ acsb,
                          const float* __restrict__ prev, const float* __restrict__ Dv,
                          const int* __restrict__ mor, u16* __restrict__ cat, int catOff)
{
    __shared__ __align__(16) u16 Xt[64 * 256];   // [p][s] bf16, XOR-swizzled, 32KB
    __shared__ __align__(16) u16 Xp[64 * 40];    // [p][k] prev bf16 (k 0..3 real), 5KB
    __shared__ float4 sBdt[256];
    __shared__ float4 sC[256];
    __shared__ float  sA2[256];

    const int c = blockIdx.x, h = blockIdx.y;
    const int tid = threadIdx.x;
    const int lane = tid & 63, w = tid >> 6;

    // ---- stage X^T (pure copy): wave w -> s in [w*32, w*32+32), p = lane ----
    {
        const int p = lane;
        const size_t colOff = 256 + h * 64 + p;
#pragma unroll
        for (int jq = 0; jq < 4; ++jq) {
            const int s0 = w * 32 + jq * 8;
            u32 wd[4];
#pragma unroll
            for (int q = 0; q < 4; ++q) {
                int gl0 = c * 256 + s0 + q * 2;
                u32 lo = (gl0     < L_SEQ) ? (u32)zxb[(size_t)gl0 * 512 + colOff] : 0u;
                u32 hi = (gl0 + 1 < L_SEQ) ? (u32)zxb[(size_t)(gl0 + 1) * 512 + colOff] : 0u;
                wd[q] = lo | (hi << 16);
            }
            u32 off = (u32)(p * 512 + s0 * 2) ^ (u32)((p & 15) << 4);
            *(uint4*)((char*)Xt + off) = make_uint4(wd[0], wd[1], wd[2], wd[3]);
        }
    }
    // ---- stage prev tile (bf16, k-slots 0..3; rest zero) ----
    if (tid < 64) {
        float4 pv = *(const float4*)(prev + (size_t)c * 1024 + h * 256 + tid * 4);
        u32 w0 = cvtpk(pv.x, pv.y), w1 = cvtpk(pv.z, pv.w);
        uint4* row = (uint4*)((char*)Xp + tid * 80);
        row[0] = make_uint4(w0, w1, 0u, 0u);
        row[1] = make_uint4(0u, 0u, 0u, 0u);
        row[2] = make_uint4(0u, 0u, 0u, 0u);
        row[3] = make_uint4(0u, 0u, 0u, 0u);
    }
    // ---- stage Bdt/C/acs2 ----
    if (tid < 256) {
        const int s = tid, gl = c * 256 + s;
        if (gl < L_SEQ) {
            const float* tr = tail + (size_t)gl * 12;
            float4 B4 = *(const float4*)tr;
            float4 C4v = *(const float4*)(tr + 4);
            float dt = dtb[(size_t)gl * 4 + h];
            sBdt[s] = make_float4(B4.x * dt, B4.y * dt, B4.z * dt, B4.w * dt);
            sC[s] = C4v;
            sA2[s] = acsb[(size_t)gl * 4 + h];
        } else {
            sBdt[s] = make_float4(0.f, 0.f, 0.f, 0.f);
            sC[s] = make_float4(0.f, 0.f, 0.f, 0.f);
            sA2[s] = 0.f;
        }
    }
    __syncthreads();

    const int rl15 = lane & 15, kg = lane >> 4;
    const int R[2] = {w * 16, 240 - w * 16};
    const float Dh = Dv[h];
    int lrow[2]; float4 C4[2]; float al2[2]; int km[2];
#pragma unroll
    for (int m = 0; m < 2; ++m) {
        lrow[m] = R[m] + rl15;
        C4[m] = sC[lrow[m]];
        al2[m] = sA2[lrow[m]];
        km[m] = R[m] >> 5;
    }

    f32x4 acc[2][4];
#pragma unroll
    for (int m = 0; m < 2; ++m)
#pragma unroll
        for (int n = 0; n < 4; ++n)
            acc[m][n] = (f32x4){0.f, 0.f, 0.f, 0.f};

    const int kmW = km[1];   // R[1] >= R[0]
    for (int ks = 0; ks <= kmW; ++ks) {
        const int s0 = ks * 32 + kg * 8;
        short8 bf[4];
#pragma unroll
        for (int n = 0; n < 4; ++n) {
            int col = n * 16 + rl15;
            u32 off = (u32)(col * 512 + ks * 64 + kg * 16) ^ (u32)((col & 15) << 4);
            bf[n] = *(const short8*)((const char*)Xt + off);
        }
        float4 Bv[8]; float a2[8];
#pragma unroll
        for (int j = 0; j < 8; ++j) { Bv[j] = sBdt[s0 + j]; a2[j] = sA2[s0 + j]; }
#pragma unroll
        for (int m = 0; m < 2; ++m) {
            if (ks > km[m]) continue;
            float vv[8];
            if (ks < km[m]) {          // fully below diagonal: no masks
#pragma unroll
                for (int j = 0; j < 8; ++j) {
                    float dot = C4[m].x * Bv[j].x + C4[m].y * Bv[j].y
                              + C4[m].z * Bv[j].z + C4[m].w * Bv[j].w;
                    vv[j] = dot * exp2f(al2[m] - a2[j]);
                }
            } else {                   // diagonal fragment
#pragma unroll
                for (int j = 0; j < 8; ++j) {
                    int s = s0 + j;
                    float dot = C4[m].x * Bv[j].x + C4[m].y * Bv[j].y
                              + C4[m].z * Bv[j].z + C4[m].w * Bv[j].w;
                    float v = dot * exp2f(al2[m] - a2[j]);
                    v = (s <= lrow[m]) ? v : 0.f;
                    vv[j] = (s == lrow[m]) ? v + Dh : v;
                }
            }
            union { u32 wd[4]; short8 v; } aw;
#pragma unroll
            for (int q = 0; q < 4; ++q) aw.wd[q] = cvtpk(vv[2 * q], vv[2 * q + 1]);
#pragma unroll
            for (int n = 0; n < 4; ++n)
                acc[m][n] = __builtin_amdgcn_mfma_f32_16x16x32_bf16(aw.v, bf[n], acc[m][n], 0, 0, 0);
        }
    }
    // ---- prev contribution as one extra MFMA k-step ----
    {
        short8 bp[4];
#pragma unroll
        for (int n = 0; n < 4; ++n) {
            int col = n * 16 + rl15;
            bp[n] = *(const short8*)((const char*)Xp + col * 80 + kg * 16);
        }
#pragma unroll
        for (int m = 0; m < 2; ++m) {
            float ea = exp2f(al2[m]);
            union { u32 wd[4]; short8 v; } aw;
            aw.wd[0] = (kg == 0) ? cvtpk(ea * C4[m].x, ea * C4[m].y) : 0u;
            aw.wd[1] = (kg == 0) ? cvtpk(ea * C4[m].z, ea * C4[m].w) : 0u;
            aw.wd[2] = 0u; aw.wd[3] = 0u;
#pragma unroll
            for (int n = 0; n < 4; ++n)
                acc[m][n] = __builtin_amdgcn_mfma_f32_16x16x32_bf16(aw.v, bp[n], acc[m][n], 0, 0, 0);
        }
    }

    // ---- epilogue: gate with pre-silu'd z, scatter bf16 ----
#pragma unroll
    for (int m = 0; m < 2; ++m) {
#pragma unroll
        for (int r = 0; r < 4; ++r) {
            const int row = R[m] + kg * 4 + r;
            const int gl = c * 256 + row;
            if (gl >= L_SEQ) continue;
            const int pos = mor[gl];
            const size_t zbase = (size_t)gl * 512 + h * 64;
            u16* orow = cat + (size_t)pos * 512 + catOff + h * 64;
#pragma unroll
            for (int n = 0; n < 4; ++n) {
                const int col = n * 16 + rl15;
                float zs = bf2f(zxb[zbase + col]);
                float y = acc[m][n][r] * zs;
                orow[col] = (u16)cvtpk(y, y);
            }
        }
    }
}

// ---------------------------------------------------------------------------
// LayerNorm over channel dim (256).
// ---------------------------------------------------------------------------
__launch_bounds__(256)
__global__ void ln_k(const float* __restrict__ pin, const float* __restrict__ g,
                     const float* __restrict__ b, float* __restrict__ pout)
{
    const int l = blockIdx.x, c = threadIdx.x;
    float v = pin[(size_t)l * 256 + c];
    float s = v, s2 = v * v;
#pragma unroll
    for (int o = 32; o > 0; o >>= 1) { s += __shfl_down(s, o); s2 += __shfl_down(s2, o); }
    __shared__ float ws0[4], ws1[4];
    if ((c & 63) == 0) { ws0[c >> 6] = s; ws1[c >> 6] = s2; }
    __syncthreads();
    float ts = ws0[0] + ws0[1] + ws0[2] + ws0[3];
    float t2 = ws1[0] + ws1[1] + ws1[2] + ws1[3];
    float mu = ts * (1.f / 256.f);
    float var = t2 * (1.f / 256.f) - mu * mu;
    float r = rsqrtf(var + 1e-6f);
    pout[(size_t)l * 256 + c] = (v - mu) * r * g[c] + b[c];
}

// ---------------------------------------------------------------------------
// Transpose (L x 256) -> (256 x L).
// ---------------------------------------------------------------------------
__global__ void transpose_k(const float* __restrict__ pin, float* __restrict__ pout)
{
    __shared__ float t[64][65];
    const int l0 = blockIdx.x * 64, c0 = blockIdx.y * 64;
    const int tx = threadIdx.x, ty = threadIdx.y;
#pragma unroll
    for (int j = 0; j < 16; ++j) {
        int row = ty + j * 4;
        int l = l0 + row;
        t[row][tx] = (l < L_SEQ) ? pin[(size_t)l * 256 + c0 + tx] : 0.f;
    }
    __syncthreads();
#pragma unroll
    for (int j = 0; j < 16; ++j) {
        int crow = ty + j * 4;
        int lcol = l0 + tx;
        if (lcol < L_SEQ) pout[(size_t)(c0 + crow) * L_SEQ + lcol] = t[tx][crow];
    }
}

// ---------------------------------------------------------------------------
extern "C" void kernel_launch(void* const* d_in, const int* in_sizes, int n_in,
                              void* d_out, int out_size, void* d_ws, size_t ws_size,
                              hipStream_t stream)
{
    const float* x        = (const float*)d_in[0];
    const float* W_in[2]  = {(const float*)d_in[1], (const float*)d_in[2]};
    const float* dt_b[2]  = {(const float*)d_in[3], (const float*)d_in[4]};
    const float* A_log[2] = {(const float*)d_in[5], (const float*)d_in[6]};
    const float* Dv[2]    = {(const float*)d_in[7], (const float*)d_in[8]};
    const float* W_out    = (const float*)d_in[9];
    const float* ln_g     = (const float*)d_in[10];
    const float* ln_b     = (const float*)d_in[11];
    const int*   mor[2]   = {(const int*)d_in[12], (const int*)d_in[13]};
    const int*   inv[2]   = {(const int*)d_in[14], (const int*)d_in[15]};

    char* ws = (char*)d_ws;
    size_t off = 0;
    auto alloc = [&](size_t bytes) { char* p = ws + off; off += (bytes + 255) & ~(size_t)255; return p; };
    u16*   zxb  = (u16*)  alloc((size_t)L_SEQ * 512 * 2);   // silu(z)|silu(x); reused as proj f32
    u16*   cat  = (u16*)  alloc((size_t)MPAD * 512 * 2);    // bf16; reused (f32) as LN out
    float* tail = (float*)alloc((size_t)L_SEQ * 12 * 4);    // silu(B)|silu(C)|dt_raw
    u16*   xg   = (u16*)  alloc((size_t)MPAD * 256 * 2);
    u16*   wbuf = (u16*)  alloc((size_t)640 * 256 * 2);
    float* dtb  = (float*)alloc((size_t)L_SEQ * 4 * 4);
    float* acsb = (float*)alloc((size_t)L_SEQ * 4 * 4);
    float* csum = (float*)alloc((size_t)NCH * 4 * 4);
    float* spart= (float*)alloc((size_t)NCH * 4 * 1024 * 4);
    float* prev = (float*)alloc((size_t)NCH * 1024 * 4);
    float* proj  = (float*)zxb;   // zxb dead after both paths' ychunk
    float* lnout = (float*)cat;   // cat dead after out-proj

    for (int path = 0; path < 2; ++path) {
        convpad_k<<<640, 256, 0, stream>>>(W_in[path], wbuf, 524, 256, 640);
        gather_k<<<507, 256, 0, stream>>>(x, inv[path], xg);
        zero_k<<<(112 * 256 + 255) / 256, 256, 0, stream>>>(xg + (size_t)L_SEQ * 256, 112 * 256);
        gemm2_k<1><<<dim3(5, 254), 256, 0, stream>>>(xg, wbuf, 256, nullptr, 0, zxb, tail);
        prep_k<<<NCH, 256, 0, stream>>>(tail, dt_b[path], A_log[path], dtb, acsb, csum);
        states_part_k<<<dim3(NCH, 4), 256, 0, stream>>>(zxb, dtb, tail, acsb, csum, spart);
        chunkscan_k<<<4, 256, 0, stream>>>(csum, spart, prev);
        ychunk3_k<<<dim3(NCH, NH), 512, 0, stream>>>(zxb, tail, dtb, acsb, prev,
                                                     Dv[path], mor[path], cat, path * 256);
    }
    zero_k<<<(112 * 512 + 255) / 256, 256, 0, stream>>>(cat + (size_t)L_SEQ * 512, 112 * 512);
    convpad_k<<<256, 256, 0, stream>>>(W_out, wbuf, 256, 512, 256);
    gemm2_k<0><<<dim3(2, 254), 256, 0, stream>>>(cat, wbuf, 512, proj, 256, nullptr, nullptr);
    ln_k<<<L_SEQ, 256, 0, stream>>>(proj, ln_g, ln_b, lnout);
    transpose_k<<<dim3(507, 4), dim3(64, 4), 0, stream>>>(lnout, (float*)d_out);
}

// Round 9
// 314.838 us; speedup vs baseline: 1.8146x; 1.2164x over previous
//
#include <hip/hip_runtime.h>
#include <cstdint>

#define L_SEQ 32400
#define HWSZ  32400
#define MPAD  32512
#define NCH   127
#define NH    4
#define LOG2E 1.4426950408889634f

typedef unsigned short u16;
typedef unsigned int   u32;
typedef __attribute__((ext_vector_type(8))) short short8;
typedef __attribute__((ext_vector_type(4))) float f32x4;

__device__ __forceinline__ float silu_f(float v) {
    float e = __expf(-v);
    return v * __builtin_amdgcn_rcpf(1.f + e);
}
__device__ __forceinline__ float softplus_f(float v) { return v > 20.f ? v : log1pf(__expf(v)); }
__device__ __forceinline__ u16 f2bf(float f) {
    u32 u = __float_as_uint(f);
    u += 0x7FFFu + ((u >> 16) & 1u);
    return (u16)(u >> 16);
}
__device__ __forceinline__ u32 cvtpk(float lo, float hi) {
    u32 r;
    asm("v_cvt_pk_bf16_f32 %0, %1, %2" : "=v"(r) : "v"(lo), "v"(hi));
    return r;
}
__device__ __forceinline__ float bf2f(u32 u) { return __uint_as_float(u << 16); }
__device__ __forceinline__ void gload16(const void* g, void* l) {
    __builtin_amdgcn_global_load_lds(
        (const __attribute__((address_space(1))) u32*)(uintptr_t)g,
        (__attribute__((address_space(3))) u32*)(u32)(uintptr_t)l,
        16, 0, 0);
}

// ---------------------------------------------------------------------------
// Gather + transpose + bf16 pack, batched over both paths (z).
// ---------------------------------------------------------------------------
__launch_bounds__(256)
__global__ void gather_k(const float* __restrict__ x, const int* __restrict__ inv0,
                         const int* __restrict__ inv1, u16* __restrict__ xg)
{
    __shared__ u16 tile[256][66];
    const int z = blockIdx.y;
    const int* __restrict__ inv = z ? inv1 : inv0;
    u16* __restrict__ xgp = xg + (size_t)z * MPAD * 256;
    const int pix0 = blockIdx.x * 64;
    const int tid = threadIdx.x;
    const int pl = tid & 63, cq = tid >> 6;
    const int pix = pix0 + pl;
    const bool pv = pix < HWSZ;
#pragma unroll 4
    for (int j = 0; j < 64; ++j) {
        int c = cq * 64 + j;
        float v = pv ? x[(size_t)c * HWSZ + pix] : 0.f;
        tile[c][pl] = f2bf(v);
    }
    __syncthreads();
    for (int i = 0; i < 64; ++i) {
        int p2 = pix0 + i;
        if (p2 < HWSZ) {
            int row = inv[p2];
            xgp[(size_t)row * 256 + tid] = tile[tid][i];
        }
    }
}

// zero n u16 elements at p + z*zstride
__global__ void zero2_k(u16* __restrict__ p, size_t zstride, int n)
{
    int i = blockIdx.x * 256 + threadIdx.x;
    if (i < n) p[(size_t)blockIdx.y * zstride + i] = 0;
}

// f32 [rows][cols] -> bf16 [gridX rows][cols]; pad rows zeroed; batched (z).
__global__ void convpad2_k(const float* __restrict__ s0, const float* __restrict__ s1,
                           u16* __restrict__ dst, int rows, int cols, size_t zstride)
{
    const int z = blockIdx.y;
    const float* __restrict__ src = z ? s1 : s0;
    u16* __restrict__ d = dst + (size_t)z * zstride;
    int r = blockIdx.x;
    for (int c = threadIdx.x; c < cols; c += 256)
        d[(size_t)r * cols + c] = (r < rows) ? f2bf(src[(size_t)r * cols + c]) : (u16)0;
}

// ---------------------------------------------------------------------------
// W-stationary bf16 MFMA GEMM.  8 waves (2M x 4N); wave = 16 rows x NFRAG*16
// cols; W fragments live in REGISTERS (loaded once); M streamed in 32-row
// tiles through double-buffered LDS with counted vmcnt.  A rows read as full
// contiguous K*2-byte lines (perfect DRAM).  Panel c0 = blockIdx.x * NFRAG*64.
// MODE 0: f32 out (out-proj).  MODE 1: in-proj fused silu/split epilogue,
// batched over paths via blockIdx.z.
// ---------------------------------------------------------------------------
template<int MODE, int K, int NFRAG>
__launch_bounds__(512, 2)
__global__ void wgemm_k(const u16* __restrict__ A, size_t aZstride,
                        const u16* __restrict__ W, size_t wZstride,
                        float* __restrict__ outF, u16* __restrict__ zxb,
                        float* __restrict__ tail)
{
    constexpr int KS = K / 32;          // MFMA k-steps
    constexpr int SLOTS = K / 8;        // 16B slots per row
    constexpr int LOADS = (32 * SLOTS) / 512;   // gload16 per thread per tile
    __shared__ u16 As[2][32 * K];

    const int z = (MODE == 1) ? blockIdx.z : 0;
    const u16* __restrict__ Ab = A + (size_t)z * aZstride;
    const u16* __restrict__ Wb = W + (size_t)z * wZstride;
    u16*   __restrict__ zxbp  = zxb  ? zxb  + (size_t)z * L_SEQ * 512 : nullptr;
    float* __restrict__ tailp = tail ? tail + (size_t)z * L_SEQ * 12  : nullptr;

    const int tid = threadIdx.x;
    const int lane = tid & 63, w8 = tid >> 6;
    const int wm = w8 >> 2, wn = w8 & 3;        // 2 x 4 wave grid
    const int rl15 = lane & 15, kg = lane >> 4;
    const int c0 = blockIdx.x * (NFRAG * 64);
    const int G = gridDim.y;
    const int NT = MPAD / 32;

    // ---- W fragments -> registers (once) ----
    short8 wf[NFRAG][KS];
#pragma unroll
    for (int f = 0; f < NFRAG; ++f) {
        const int row = c0 + (wn * NFRAG + f) * 16 + rl15;
#pragma unroll
        for (int ks = 0; ks < KS; ++ks)
            wf[f][ks] = *(const short8*)(Wb + (size_t)row * K + ks * 32 + kg * 8);
    }

    auto stage = [&](int t, int buf) {
        const u16* src = Ab + (size_t)t * 32 * K;
#pragma unroll
        for (int i = 0; i < LOADS; ++i) {
            int ch = i * 512 + tid;
            int row = ch / SLOTS, slot = ch % SLOTS;
            int sw = slot ^ (row & 7);
            gload16(src + (size_t)row * K + sw * 8, (char*)As[buf] + ch * 16);
        }
    };

    int t = blockIdx.y;
    stage(t, 0);
    asm volatile("s_waitcnt vmcnt(0)" ::: "memory");  // drain W loads + tile0
    __builtin_amdgcn_s_barrier();
    int cur = 0;

    for (; t < NT; t += G) {
        const int nxt = t + G;
        if (nxt < NT) {
            stage(nxt, cur ^ 1);
            if constexpr (LOADS == 2)
                asm volatile("s_waitcnt vmcnt(2)" ::: "memory");
            else
                asm volatile("s_waitcnt vmcnt(4)" ::: "memory");
        } else {
            asm volatile("s_waitcnt vmcnt(0)" ::: "memory");
        }
        __builtin_amdgcn_s_barrier();        // all waves' cur loads landed

        f32x4 acc[NFRAG];
#pragma unroll
        for (int f = 0; f < NFRAG; ++f) acc[f] = (f32x4){0.f, 0.f, 0.f, 0.f};
        const char* Al = (const char*)As[cur];
        const int row = wm * 16 + rl15;
        __builtin_amdgcn_s_setprio(1);
#pragma unroll
        for (int ks = 0; ks < KS; ++ks) {
            const int sw = (ks * 4 + kg) ^ (row & 7);
            short8 a = *(const short8*)(Al + row * (K * 2) + sw * 16);
#pragma unroll
            for (int f = 0; f < NFRAG; ++f)
                acc[f] = __builtin_amdgcn_mfma_f32_16x16x32_bf16(a, wf[f][ks], acc[f], 0, 0, 0);
        }
        __builtin_amdgcn_s_setprio(0);
        __builtin_amdgcn_s_barrier();        // cur free for overwrite

        // epilogue (overlaps next stage's flight)
#pragma unroll
        for (int f = 0; f < NFRAG; ++f) {
            const int col = c0 + (wn * NFRAG + f) * 16 + rl15;
#pragma unroll
            for (int r = 0; r < 4; ++r) {
                const int gl = t * 32 + wm * 16 + kg * 4 + r;
                if (gl >= L_SEQ) continue;
                float v = acc[f][r];
                if (MODE == 0) {
                    outF[(size_t)gl * 256 + col] = v;
                } else {
                    if (col < 512) {
                        float s = silu_f(v);
                        zxbp[(size_t)gl * 512 + col] = (u16)cvtpk(s, s);
                    } else if (col < 520) {
                        tailp[(size_t)gl * 12 + (col - 512)] = silu_f(v);
                    } else if (col < 524) {
                        tailp[(size_t)gl * 12 + (col - 512)] = v;
                    }
                }
            }
        }
        cur ^= 1;
    }
}

// ---------------------------------------------------------------------------
// Per-chunk prep (batched over paths via blockIdx.y).
// ---------------------------------------------------------------------------
__launch_bounds__(256)
__global__ void prep_k(const float* __restrict__ tail, const float* __restrict__ db0,
                       const float* __restrict__ db1, const float* __restrict__ al0,
                       const float* __restrict__ al1, float* __restrict__ dtb,
                       float* __restrict__ acsb, float* __restrict__ csum)
{
    const int z = blockIdx.y;
    const float* dt_bias = z ? db1 : db0;
    const float* A_log = z ? al1 : al0;
    const float* tl = tail + (size_t)z * L_SEQ * 12;
    float* dtbp = dtb + (size_t)z * L_SEQ * 4;
    float* acsp = acsb + (size_t)z * L_SEQ * 4;
    float* csp = csum + (size_t)z * NCH * 4;

    const int c = blockIdx.x;
    const int l = threadIdx.x;
    const int lane = l & 63, w = l >> 6;
    const int gl = c * 256 + l;
    const bool valid = gl < L_SEQ;
    float v[NH] = {0.f, 0.f, 0.f, 0.f};
    if (valid) {
        float4 dv = *(const float4*)(tl + (size_t)gl * 12 + 8);
        const float* dp = (const float*)&dv;
#pragma unroll
        for (int h = 0; h < NH; ++h) {
            float dt = softplus_f(dp[h] + dt_bias[h]);
            dtbp[(size_t)gl * 4 + h] = dt;
            v[h] = -__expf(A_log[h]) * LOG2E * dt;
        }
    }
#pragma unroll
    for (int off = 1; off < 64; off <<= 1) {
#pragma unroll
        for (int h = 0; h < NH; ++h) {
            float tt = __shfl_up(v[h], off, 64);
            if (lane >= off) v[h] += tt;
        }
    }
    __shared__ float wsum[4][NH];
    if (lane == 63)
#pragma unroll
        for (int h = 0; h < NH; ++h) wsum[w][h] = v[h];
    __syncthreads();
#pragma unroll
    for (int h = 0; h < NH; ++h) {
        float o = 0.f;
#pragma unroll
        for (int w2 = 0; w2 < 4; ++w2) if (w2 < w) o += wsum[w2][h];
        v[h] += o;
    }
    if (valid)
#pragma unroll
        for (int h = 0; h < NH; ++h) acsp[(size_t)gl * 4 + h] = v[h];
    if (l == 255)
#pragma unroll
        for (int h = 0; h < NH; ++h) csp[c * 4 + h] = v[h];
}

// ---------------------------------------------------------------------------
// Chunk-end states, partial (batched: blockIdx.z = path).
// ---------------------------------------------------------------------------
__launch_bounds__(256)
__global__ void states_part_k(const u16* __restrict__ zxb, const float* __restrict__ dtb,
                              const float* __restrict__ tail, const float* __restrict__ acsb,
                              const float* __restrict__ csum, float* __restrict__ spart)
{
    const int z = blockIdx.z;
    const u16* zxp = zxb + (size_t)z * L_SEQ * 512;
    const float* dtbp = dtb + (size_t)z * L_SEQ * 4;
    const float* tl = tail + (size_t)z * L_SEQ * 12;
    const float* acsp = acsb + (size_t)z * L_SEQ * 4;
    const float* csp = csum + (size_t)z * NCH * 4;
    float* spp = spart + (size_t)z * NCH * 4096;

    __shared__ float coef[64][16];
    const int c = blockIdx.x, q = blockIdx.y;
    const int tid = threadIdx.x;
    {
        const int l_loc = tid >> 2, h = tid & 3;
        const int gl = c * 256 + q * 64 + l_loc;
        float4 Bv = make_float4(0.f, 0.f, 0.f, 0.f);
        float e = 0.f;
        if (gl < L_SEQ) {
            Bv = *(const float4*)(tl + (size_t)gl * 12);
            e = exp2f(csp[c * 4 + h] - acsp[(size_t)gl * 4 + h]) * dtbp[(size_t)gl * 4 + h];
        }
        *(float4*)&coef[l_loc][h * 4] = make_float4(Bv.x * e, Bv.y * e, Bv.z * e, Bv.w * e);
    }
    __syncthreads();
    const int h = tid >> 6;
    f32x4 acc = (f32x4){0.f, 0.f, 0.f, 0.f};
#pragma unroll 4
    for (int j = 0; j < 64; ++j) {
        const int gl = c * 256 + q * 64 + j;
        float xs = 0.f;
        if (gl < L_SEQ) xs = bf2f(zxp[(size_t)gl * 512 + 256 + tid]);
        float4 cf = *(const float4*)&coef[j][h * 4];
        acc[0] += cf.x * xs; acc[1] += cf.y * xs;
        acc[2] += cf.z * xs; acc[3] += cf.w * xs;
    }
    *(f32x4*)(spp + ((size_t)(c * 4 + q) * 256 + tid) * 4) = acc;
}

// ---------------------------------------------------------------------------
// Inter-chunk scan with fused q-reduction (batched: blockIdx.y = path).
// ---------------------------------------------------------------------------
__launch_bounds__(256)
__global__ void chunkscan_k(const float* __restrict__ csum, const float* __restrict__ spart,
                            float* __restrict__ prev)
{
    const int z = blockIdx.y;
    const float* csp = csum + (size_t)z * NCH * 4;
    const float* spp = spart + (size_t)z * NCH * 4096;
    float* prp = prev + (size_t)z * NCH * 1024;

    const int h = blockIdx.x;
    const int tid = threadIdx.x;
    __shared__ float ecs[NCH];
    if (tid < NCH) ecs[tid] = exp2f(csp[tid * 4 + h]);
    __syncthreads();
    float run = 0.f;
#pragma unroll 2
    for (int c = 0; c < NCH; ++c) {
        const float* sp = spp + (size_t)(c * 4) * 1024 + h * 256 + tid;
        float s = sp[0] + sp[1024] + sp[2048] + sp[3072];
        prp[(size_t)c * 1024 + h * 256 + tid] = run;
        run = run * ecs[c] + s;
    }
}

// ---------------------------------------------------------------------------
// MFMA per-chunk output (batched: blockIdx.z = path).
// ---------------------------------------------------------------------------
__launch_bounds__(512, 2)
__global__ void ychunk3_k(const u16* __restrict__ zxb, const float* __restrict__ tail,
                          const float* __restrict__ dtb, const float* __restrict__ acsb,
                          const float* __restrict__ prev, const float* __restrict__ Dv0,
                          const float* __restrict__ Dv1, const int* __restrict__ mor0,
                          const int* __restrict__ mor1, u16* __restrict__ cat)
{
    const int z = blockIdx.z;
    const u16* zxp = zxb + (size_t)z * L_SEQ * 512;
    const float* tl = tail + (size_t)z * L_SEQ * 12;
    const float* dtbp = dtb + (size_t)z * L_SEQ * 4;
    const float* acsp = acsb + (size_t)z * L_SEQ * 4;
    const float* prp = prev + (size_t)z * NCH * 1024;
    const float* Dv = z ? Dv1 : Dv0;
    const int* mor = z ? mor1 : mor0;
    const int catOff = z * 256;

    __shared__ __align__(16) u16 Xt[64 * 256];
    __shared__ __align__(16) u16 Xp[64 * 40];
    __shared__ float4 sBdt[256];
    __shared__ float4 sC[256];
    __shared__ float  sA2[256];

    const int c = blockIdx.x, h = blockIdx.y;
    const int tid = threadIdx.x;
    const int lane = tid & 63, w = tid >> 6;

    {
        const int p = lane;
        const size_t colOff = 256 + h * 64 + p;
#pragma unroll
        for (int jq = 0; jq < 4; ++jq) {
            const int s0 = w * 32 + jq * 8;
            u32 wd[4];
#pragma unroll
            for (int q = 0; q < 4; ++q) {
                int gl0 = c * 256 + s0 + q * 2;
                u32 lo = (gl0     < L_SEQ) ? (u32)zxp[(size_t)gl0 * 512 + colOff] : 0u;
                u32 hi = (gl0 + 1 < L_SEQ) ? (u32)zxp[(size_t)(gl0 + 1) * 512 + colOff] : 0u;
                wd[q] = lo | (hi << 16);
            }
            u32 off = (u32)(p * 512 + s0 * 2) ^ (u32)((p & 15) << 4);
            *(uint4*)((char*)Xt + off) = make_uint4(wd[0], wd[1], wd[2], wd[3]);
        }
    }
    if (tid < 64) {
        float4 pv = *(const float4*)(prp + (size_t)c * 1024 + h * 256 + tid * 4);
        u32 w0 = cvtpk(pv.x, pv.y), w1 = cvtpk(pv.z, pv.w);
        uint4* row = (uint4*)((char*)Xp + tid * 80);
        row[0] = make_uint4(w0, w1, 0u, 0u);
        row[1] = make_uint4(0u, 0u, 0u, 0u);
        row[2] = make_uint4(0u, 0u, 0u, 0u);
        row[3] = make_uint4(0u, 0u, 0u, 0u);
    }
    if (tid < 256) {
        const int s = tid, gl = c * 256 + s;
        if (gl < L_SEQ) {
            const float* tr = tl + (size_t)gl * 12;
            float4 B4 = *(const float4*)tr;
            float4 C4v = *(const float4*)(tr + 4);
            float dt = dtbp[(size_t)gl * 4 + h];
            sBdt[s] = make_float4(B4.x * dt, B4.y * dt, B4.z * dt, B4.w * dt);
            sC[s] = C4v;
            sA2[s] = acsp[(size_t)gl * 4 + h];
        } else {
            sBdt[s] = make_float4(0.f, 0.f, 0.f, 0.f);
            sC[s] = make_float4(0.f, 0.f, 0.f, 0.f);
            sA2[s] = 0.f;
        }
    }
    __syncthreads();

    const int rl15 = lane & 15, kg = lane >> 4;
    const int R[2] = {w * 16, 240 - w * 16};
    const float Dh = Dv[h];
    int lrow[2]; float4 C4[2]; float al2[2]; int km[2];
#pragma unroll
    for (int m = 0; m < 2; ++m) {
        lrow[m] = R[m] + rl15;
        C4[m] = sC[lrow[m]];
        al2[m] = sA2[lrow[m]];
        km[m] = R[m] >> 5;
    }

    f32x4 acc[2][4];
#pragma unroll
    for (int m = 0; m < 2; ++m)
#pragma unroll
        for (int n = 0; n < 4; ++n)
            acc[m][n] = (f32x4){0.f, 0.f, 0.f, 0.f};

    const int kmW = km[1];
    for (int ks = 0; ks <= kmW; ++ks) {
        const int s0 = ks * 32 + kg * 8;
        short8 bf[4];
#pragma unroll
        for (int n = 0; n < 4; ++n) {
            int col = n * 16 + rl15;
            u32 off = (u32)(col * 512 + ks * 64 + kg * 16) ^ (u32)((col & 15) << 4);
            bf[n] = *(const short8*)((const char*)Xt + off);
        }
        float4 Bv[8]; float a2[8];
#pragma unroll
        for (int j = 0; j < 8; ++j) { Bv[j] = sBdt[s0 + j]; a2[j] = sA2[s0 + j]; }
#pragma unroll
        for (int m = 0; m < 2; ++m) {
            if (ks > km[m]) continue;
            float vv[8];
            if (ks < km[m]) {
#pragma unroll
                for (int j = 0; j < 8; ++j) {
                    float dot = C4[m].x * Bv[j].x + C4[m].y * Bv[j].y
                              + C4[m].z * Bv[j].z + C4[m].w * Bv[j].w;
                    vv[j] = dot * exp2f(al2[m] - a2[j]);
                }
            } else {
#pragma unroll
                for (int j = 0; j < 8; ++j) {
                    int s = s0 + j;
                    float dot = C4[m].x * Bv[j].x + C4[m].y * Bv[j].y
                              + C4[m].z * Bv[j].z + C4[m].w * Bv[j].w;
                    float v = dot * exp2f(al2[m] - a2[j]);
                    v = (s <= lrow[m]) ? v : 0.f;
                    vv[j] = (s == lrow[m]) ? v + Dh : v;
                }
            }
            union { u32 wd[4]; short8 v; } aw;
#pragma unroll
            for (int q = 0; q < 4; ++q) aw.wd[q] = cvtpk(vv[2 * q], vv[2 * q + 1]);
#pragma unroll
            for (int n = 0; n < 4; ++n)
                acc[m][n] = __builtin_amdgcn_mfma_f32_16x16x32_bf16(aw.v, bf[n], acc[m][n], 0, 0, 0);
        }
    }
    {
        short8 bp[4];
#pragma unroll
        for (int n = 0; n < 4; ++n) {
            int col = n * 16 + rl15;
            bp[n] = *(const short8*)((const char*)Xp + col * 80 + kg * 16);
        }
#pragma unroll
        for (int m = 0; m < 2; ++m) {
            float ea = exp2f(al2[m]);
            union { u32 wd[4]; short8 v; } aw;
            aw.wd[0] = (kg == 0) ? cvtpk(ea * C4[m].x, ea * C4[m].y) : 0u;
            aw.wd[1] = (kg == 0) ? cvtpk(ea * C4[m].z, ea * C4[m].w) : 0u;
            aw.wd[2] = 0u; aw.wd[3] = 0u;
#pragma unroll
            for (int n = 0; n < 4; ++n)
                acc[m][n] = __builtin_amdgcn_mfma_f32_16x16x32_bf16(aw.v, bp[n], acc[m][n], 0, 0, 0);
        }
    }

#pragma unroll
    for (int m = 0; m < 2; ++m) {
#pragma unroll
        for (int r = 0; r < 4; ++r) {
            const int row = R[m] + kg * 4 + r;
            const int gl = c * 256 + row;
            if (gl >= L_SEQ) continue;
            const int pos = mor[gl];
            const size_t zbase = (size_t)gl * 512 + h * 64;
            u16* orow = cat + (size_t)pos * 512 + catOff + h * 64;
#pragma unroll
            for (int n = 0; n < 4; ++n) {
                const int col = n * 16 + rl15;
                float zs = bf2f(zxp[zbase + col]);
                float y = acc[m][n][r] * zs;
                orow[col] = (u16)cvtpk(y, y);
            }
        }
    }
}

// ---------------------------------------------------------------------------
// LayerNorm over channel dim (256).
// ---------------------------------------------------------------------------
__launch_bounds__(256)
__global__ void ln_k(const float* __restrict__ pin, const float* __restrict__ g,
                     const float* __restrict__ b, float* __restrict__ pout)
{
    const int l = blockIdx.x, c = threadIdx.x;
    float v = pin[(size_t)l * 256 + c];
    float s = v, s2 = v * v;
#pragma unroll
    for (int o = 32; o > 0; o >>= 1) { s += __shfl_down(s, o); s2 += __shfl_down(s2, o); }
    __shared__ float ws0[4], ws1[4];
    if ((c & 63) == 0) { ws0[c >> 6] = s; ws1[c >> 6] = s2; }
    __syncthreads();
    float ts = ws0[0] + ws0[1] + ws0[2] + ws0[3];
    float t2 = ws1[0] + ws1[1] + ws1[2] + ws1[3];
    float mu = ts * (1.f / 256.f);
    float var = t2 * (1.f / 256.f) - mu * mu;
    float r = rsqrtf(var + 1e-6f);
    pout[(size_t)l * 256 + c] = (v - mu) * r * g[c] + b[c];
}

// ---------------------------------------------------------------------------
// Transpose (L x 256) -> (256 x L).
// ---------------------------------------------------------------------------
__global__ void transpose_k(const float* __restrict__ pin, float* __restrict__ pout)
{
    __shared__ float t[64][65];
    const int l0 = blockIdx.x * 64, c0 = blockIdx.y * 64;
    const int tx = threadIdx.x, ty = threadIdx.y;
#pragma unroll
    for (int j = 0; j < 16; ++j) {
        int row = ty + j * 4;
        int l = l0 + row;
        t[row][tx] = (l < L_SEQ) ? pin[(size_t)l * 256 + c0 + tx] : 0.f;
    }
    __syncthreads();
#pragma unroll
    for (int j = 0; j < 16; ++j) {
        int crow = ty + j * 4;
        int lcol = l0 + tx;
        if (lcol < L_SEQ) pout[(size_t)(c0 + crow) * L_SEQ + lcol] = t[tx][crow];
    }
}

// ---------------------------------------------------------------------------
extern "C" void kernel_launch(void* const* d_in, const int* in_sizes, int n_in,
                              void* d_out, int out_size, void* d_ws, size_t ws_size,
                              hipStream_t stream)
{
    const float* x      = (const float*)d_in[0];
    const float* W_in0  = (const float*)d_in[1];
    const float* W_in1  = (const float*)d_in[2];
    const float* dt_b0  = (const float*)d_in[3];
    const float* dt_b1  = (const float*)d_in[4];
    const float* A_log0 = (const float*)d_in[5];
    const float* A_log1 = (const float*)d_in[6];
    const float* Dv0    = (const float*)d_in[7];
    const float* Dv1    = (const float*)d_in[8];
    const float* W_out  = (const float*)d_in[9];
    const float* ln_g   = (const float*)d_in[10];
    const float* ln_b   = (const float*)d_in[11];
    const int*   mor0   = (const int*)d_in[12];
    const int*   mor1   = (const int*)d_in[13];
    const int*   inv0   = (const int*)d_in[14];
    const int*   inv1   = (const int*)d_in[15];

    char* ws = (char*)d_ws;
    size_t off = 0;
    auto alloc = [&](size_t bytes) { char* p = ws + off; off += (bytes + 255) & ~(size_t)255; return p; };
    u16*   zxb   = (u16*)  alloc((size_t)2 * L_SEQ * 512 * 2);  // per-path; reused as proj f32
    u16*   cat   = (u16*)  alloc((size_t)MPAD * 512 * 2);       // reused (f32) as LN out
    float* tail  = (float*)alloc((size_t)2 * L_SEQ * 12 * 4);
    u16*   xg    = (u16*)  alloc((size_t)2 * MPAD * 256 * 2);
    u16*   wbufI = (u16*)  alloc((size_t)2 * 640 * 256 * 2);
    u16*   wbufO = (u16*)  alloc((size_t)256 * 512 * 2);
    float* dtb   = (float*)alloc((size_t)2 * L_SEQ * 4 * 4);
    float* acsb  = (float*)alloc((size_t)2 * L_SEQ * 4 * 4);
    float* csum  = (float*)alloc((size_t)2 * NCH * 4 * 4);
    float* spart = (float*)alloc((size_t)2 * NCH * 4096 * 4);
    float* prev  = (float*)alloc((size_t)2 * NCH * 1024 * 4);
    float* proj  = (float*)zxb;
    float* lnout = (float*)cat;

    // prep inputs (both paths batched)
    convpad2_k<<<dim3(640, 2), 256, 0, stream>>>(W_in0, W_in1, wbufI, 524, 256, (size_t)640 * 256);
    convpad2_k<<<dim3(256, 1), 256, 0, stream>>>(W_out, W_out, wbufO, 256, 512, 0);
    gather_k<<<dim3(507, 2), 256, 0, stream>>>(x, inv0, inv1, xg);
    zero2_k<<<dim3(112, 2), 256, 0, stream>>>(xg + (size_t)L_SEQ * 256, (size_t)MPAD * 256, 112 * 256);

    // in-proj, both paths, W-stationary (3 panels x 43 groups x 2 paths)
    wgemm_k<1, 256, 3><<<dim3(3, 43, 2), 512, 0, stream>>>(
        xg, (size_t)MPAD * 256, wbufI, (size_t)640 * 256, nullptr, zxb, tail);

    prep_k<<<dim3(NCH, 2), 256, 0, stream>>>(tail, dt_b0, dt_b1, A_log0, A_log1, dtb, acsb, csum);
    states_part_k<<<dim3(NCH, 4, 2), 256, 0, stream>>>(zxb, dtb, tail, acsb, csum, spart);
    chunkscan_k<<<dim3(4, 2), 256, 0, stream>>>(csum, spart, prev);
    ychunk3_k<<<dim3(NCH, NH, 2), 512, 0, stream>>>(zxb, tail, dtb, acsb, prev,
                                                    Dv0, Dv1, mor0, mor1, cat);

    zero2_k<<<dim3(224, 1), 256, 0, stream>>>(cat + (size_t)L_SEQ * 512, 0, 112 * 512);
    // out-proj (2 panels x 128 groups)
    wgemm_k<0, 512, 2><<<dim3(2, 128, 1), 512, 0, stream>>>(
        cat, 0, wbufO, 0, proj, nullptr, nullptr);

    ln_k<<<L_SEQ, 256, 0, stream>>>(proj, ln_g, ln_b, lnout);
    transpose_k<<<dim3(507, 4), dim3(64, 4), 0, stream>>>(lnout, (float*)d_out);
}

// Round 10
// 304.885 us; speedup vs baseline: 1.8739x; 1.0326x over previous
//
#include <hip/hip_runtime.h>
#include <cstdint>

#define L_SEQ 32400
#define HWSZ  32400
#define MPAD  32512
#define NCH   127
#define NH    4
#define LOG2E 1.4426950408889634f

typedef unsigned short u16;
typedef unsigned int   u32;
typedef __attribute__((ext_vector_type(8))) short short8;
typedef __attribute__((ext_vector_type(4))) float f32x4;

__device__ __forceinline__ float silu_f(float v) {
    float e = __expf(-v);
    return v * __builtin_amdgcn_rcpf(1.f + e);
}
__device__ __forceinline__ float softplus_f(float v) { return v > 20.f ? v : log1pf(__expf(v)); }
__device__ __forceinline__ u16 f2bf(float f) {
    u32 u = __float_as_uint(f);
    u += 0x7FFFu + ((u >> 16) & 1u);
    return (u16)(u >> 16);
}
__device__ __forceinline__ u32 cvtpk(float lo, float hi) {
    u32 r;
    asm("v_cvt_pk_bf16_f32 %0, %1, %2" : "=v"(r) : "v"(lo), "v"(hi));
    return r;
}
__device__ __forceinline__ float bf2f(u32 u) { return __uint_as_float(u << 16); }
__device__ __forceinline__ void gload16(const void* g, void* l) {
    __builtin_amdgcn_global_load_lds(
        (const __attribute__((address_space(1))) u32*)(uintptr_t)g,
        (__attribute__((address_space(3))) u32*)(u32)(uintptr_t)l,
        16, 0, 0);
}
template<int N> __device__ __forceinline__ void waitvm() {
    if constexpr (N == 0)       asm volatile("s_waitcnt vmcnt(0)" ::: "memory");
    else if constexpr (N == 2)  asm volatile("s_waitcnt vmcnt(2)" ::: "memory");
    else if constexpr (N == 4)  asm volatile("s_waitcnt vmcnt(4)" ::: "memory");
    else if constexpr (N == 6)  asm volatile("s_waitcnt vmcnt(6)" ::: "memory");
    else if constexpr (N == 8)  asm volatile("s_waitcnt vmcnt(8)" ::: "memory");
    else if constexpr (N == 12) asm volatile("s_waitcnt vmcnt(12)" ::: "memory");
}

// ---------------------------------------------------------------------------
// Gather + transpose + bf16 pack, batched over both paths (z).
// ---------------------------------------------------------------------------
__launch_bounds__(256)
__global__ void gather_k(const float* __restrict__ x, const int* __restrict__ inv0,
                         const int* __restrict__ inv1, u16* __restrict__ xg)
{
    __shared__ u16 tile[256][66];
    const int z = blockIdx.y;
    const int* __restrict__ inv = z ? inv1 : inv0;
    u16* __restrict__ xgp = xg + (size_t)z * MPAD * 256;
    const int pix0 = blockIdx.x * 64;
    const int tid = threadIdx.x;
    const int pl = tid & 63, cq = tid >> 6;
    const int pix = pix0 + pl;
    const bool pv = pix < HWSZ;
#pragma unroll 4
    for (int j = 0; j < 64; ++j) {
        int c = cq * 64 + j;
        float v = pv ? x[(size_t)c * HWSZ + pix] : 0.f;
        tile[c][pl] = f2bf(v);
    }
    __syncthreads();
    for (int i = 0; i < 64; ++i) {
        int p2 = pix0 + i;
        if (p2 < HWSZ) {
            int row = inv[p2];
            xgp[(size_t)row * 256 + tid] = tile[tid][i];
        }
    }
}

__global__ void zero2_k(u16* __restrict__ p, size_t zstride, int n)
{
    int i = blockIdx.x * 256 + threadIdx.x;
    if (i < n) p[(size_t)blockIdx.y * zstride + i] = 0;
}

__global__ void convpad2_k(const float* __restrict__ s0, const float* __restrict__ s1,
                           u16* __restrict__ dst, int rows, int cols, size_t zstride)
{
    const int z = blockIdx.y;
    const float* __restrict__ src = z ? s1 : s0;
    u16* __restrict__ d = dst + (size_t)z * zstride;
    int r = blockIdx.x;
    for (int c = threadIdx.x; c < cols; c += 256)
        d[(size_t)r * cols + c] = (r < rows) ? f2bf(src[(size_t)r * cols + c]) : (u16)0;
}

// ---------------------------------------------------------------------------
// W-stationary bf16 MFMA GEMM, DEPTH-deep ring-buffered M-streaming.
// 8 waves (2M x 4N); W fragments in registers (loaded once); 32-row A tiles
// streamed through DEPTH LDS buffers with counted vmcnt (loads stay in
// flight ~DEPTH-1 iterations ≈ HBM latency).  Stage issued before epilogue
// stores so prefetch queues ahead.  MODE 0: f32 out. MODE 1: in-proj fused
// silu/split epilogue, batched over paths via blockIdx.z.
// ---------------------------------------------------------------------------
template<int MODE, int K, int NFRAG, int DEPTH>
__launch_bounds__(512, 2)
__global__ void wgemm_k(const u16* __restrict__ A, size_t aZstride,
                        const u16* __restrict__ W, size_t wZstride,
                        float* __restrict__ outF, u16* __restrict__ zxb,
                        float* __restrict__ tail)
{
    constexpr int KS = K / 32;
    constexpr int SLOTS = K / 8;
    constexpr int LOADS = (32 * SLOTS) / 512;
    __shared__ u16 As[DEPTH][32 * K];

    const int z = (MODE == 1) ? blockIdx.z : 0;
    const u16* __restrict__ Ab = A + (size_t)z * aZstride;
    const u16* __restrict__ Wb = W + (size_t)z * wZstride;
    u16*   __restrict__ zxbp  = zxb  ? zxb  + (size_t)z * L_SEQ * 512 : nullptr;
    float* __restrict__ tailp = tail ? tail + (size_t)z * L_SEQ * 12  : nullptr;

    const int tid = threadIdx.x;
    const int lane = tid & 63, w8 = tid >> 6;
    const int wm = w8 >> 2, wn = w8 & 3;
    const int rl15 = lane & 15, kg = lane >> 4;
    const int c0 = blockIdx.x * (NFRAG * 64);
    const int G = gridDim.y;
    const int NT = MPAD / 32;
    const int t0 = blockIdx.y;

    // ---- W fragments -> registers (once) ----
    short8 wf[NFRAG][KS];
#pragma unroll
    for (int f = 0; f < NFRAG; ++f) {
        const int row = c0 + (wn * NFRAG + f) * 16 + rl15;
#pragma unroll
        for (int ks = 0; ks < KS; ++ks)
            wf[f][ks] = *(const short8*)(Wb + (size_t)row * K + ks * 32 + kg * 8);
    }

    auto stage = [&](int t, int buf) {
        const u16* src = Ab + (size_t)t * 32 * K;
#pragma unroll
        for (int i = 0; i < LOADS; ++i) {
            int ch = i * 512 + tid;
            int row = ch / SLOTS, slot = ch % SLOTS;
            int sw = slot ^ (row & 7);
            gload16(src + (size_t)row * K + sw * 8, (char*)As[buf] + ch * 16);
        }
    };

    // ---- prologue: fill the ring ----
#pragma unroll
    for (int i = 0; i < DEPTH; ++i) {
        int tt = t0 + i * G;
        if (tt < NT) stage(tt, i);
    }

    int it = 0;
    for (int t = t0; t < NT; t += G, ++it) {
        const int buf = it % DEPTH;
        if (t + (DEPTH - 1) * G < NT) waitvm<(DEPTH - 1) * LOADS>();
        else                          waitvm<0>();
        __builtin_amdgcn_s_barrier();

        f32x4 acc[NFRAG];
#pragma unroll
        for (int f = 0; f < NFRAG; ++f) acc[f] = (f32x4){0.f, 0.f, 0.f, 0.f};
        const char* Al = (const char*)As[buf];
        const int row = wm * 16 + rl15;
        __builtin_amdgcn_s_setprio(1);
#pragma unroll
        for (int ks = 0; ks < KS; ++ks) {
            const int sw = (ks * 4 + kg) ^ (row & 7);
            short8 a = *(const short8*)(Al + row * (K * 2) + sw * 16);
#pragma unroll
            for (int f = 0; f < NFRAG; ++f)
                acc[f] = __builtin_amdgcn_mfma_f32_16x16x32_bf16(a, wf[f][ks], acc[f], 0, 0, 0);
        }
        __builtin_amdgcn_s_setprio(0);
        __builtin_amdgcn_s_barrier();        // buf free for overwrite

        const int nxt = t + DEPTH * G;
        if (nxt < NT) stage(nxt, buf);       // prefetch ahead of stores

        // epilogue (stores queue behind the prefetch)
#pragma unroll
        for (int f = 0; f < NFRAG; ++f) {
            const int col = c0 + (wn * NFRAG + f) * 16 + rl15;
#pragma unroll
            for (int r = 0; r < 4; ++r) {
                const int gl = t * 32 + wm * 16 + kg * 4 + r;
                if (gl >= L_SEQ) continue;
                float v = acc[f][r];
                if (MODE == 0) {
                    outF[(size_t)gl * 256 + col] = v;
                } else {
                    if (col < 512) {
                        float s = silu_f(v);
                        zxbp[(size_t)gl * 512 + col] = (u16)cvtpk(s, s);
                    } else if (col < 520) {
                        tailp[(size_t)gl * 12 + (col - 512)] = silu_f(v);
                    } else if (col < 524) {
                        tailp[(size_t)gl * 12 + (col - 512)] = v;
                    }
                }
            }
        }
    }
}

// ---------------------------------------------------------------------------
// Per-chunk prep (batched over paths via blockIdx.y).
// ---------------------------------------------------------------------------
__launch_bounds__(256)
__global__ void prep_k(const float* __restrict__ tail, const float* __restrict__ db0,
                       const float* __restrict__ db1, const float* __restrict__ al0,
                       const float* __restrict__ al1, float* __restrict__ dtb,
                       float* __restrict__ acsb, float* __restrict__ csum)
{
    const int z = blockIdx.y;
    const float* dt_bias = z ? db1 : db0;
    const float* A_log = z ? al1 : al0;
    const float* tl = tail + (size_t)z * L_SEQ * 12;
    float* dtbp = dtb + (size_t)z * L_SEQ * 4;
    float* acsp = acsb + (size_t)z * L_SEQ * 4;
    float* csp = csum + (size_t)z * NCH * 4;

    const int c = blockIdx.x;
    const int l = threadIdx.x;
    const int lane = l & 63, w = l >> 6;
    const int gl = c * 256 + l;
    const bool valid = gl < L_SEQ;
    float v[NH] = {0.f, 0.f, 0.f, 0.f};
    if (valid) {
        float4 dv = *(const float4*)(tl + (size_t)gl * 12 + 8);
        const float* dp = (const float*)&dv;
#pragma unroll
        for (int h = 0; h < NH; ++h) {
            float dt = softplus_f(dp[h] + dt_bias[h]);
            dtbp[(size_t)gl * 4 + h] = dt;
            v[h] = -__expf(A_log[h]) * LOG2E * dt;
        }
    }
#pragma unroll
    for (int off = 1; off < 64; off <<= 1) {
#pragma unroll
        for (int h = 0; h < NH; ++h) {
            float tt = __shfl_up(v[h], off, 64);
            if (lane >= off) v[h] += tt;
        }
    }
    __shared__ float wsum[4][NH];
    if (lane == 63)
#pragma unroll
        for (int h = 0; h < NH; ++h) wsum[w][h] = v[h];
    __syncthreads();
#pragma unroll
    for (int h = 0; h < NH; ++h) {
        float o = 0.f;
#pragma unroll
        for (int w2 = 0; w2 < 4; ++w2) if (w2 < w) o += wsum[w2][h];
        v[h] += o;
    }
    if (valid)
#pragma unroll
        for (int h = 0; h < NH; ++h) acsp[(size_t)gl * 4 + h] = v[h];
    if (l == 255)
#pragma unroll
        for (int h = 0; h < NH; ++h) csp[c * 4 + h] = v[h];
}

// ---------------------------------------------------------------------------
// Chunk-end states, partial (batched: blockIdx.z = path).
// ---------------------------------------------------------------------------
__launch_bounds__(256)
__global__ void states_part_k(const u16* __restrict__ zxb, const float* __restrict__ dtb,
                              const float* __restrict__ tail, const float* __restrict__ acsb,
                              const float* __restrict__ csum, float* __restrict__ spart)
{
    const int z = blockIdx.z;
    const u16* zxp = zxb + (size_t)z * L_SEQ * 512;
    const float* dtbp = dtb + (size_t)z * L_SEQ * 4;
    const float* tl = tail + (size_t)z * L_SEQ * 12;
    const float* acsp = acsb + (size_t)z * L_SEQ * 4;
    const float* csp = csum + (size_t)z * NCH * 4;
    float* spp = spart + (size_t)z * NCH * 4096;

    __shared__ float coef[64][16];
    const int c = blockIdx.x, q = blockIdx.y;
    const int tid = threadIdx.x;
    {
        const int l_loc = tid >> 2, h = tid & 3;
        const int gl = c * 256 + q * 64 + l_loc;
        float4 Bv = make_float4(0.f, 0.f, 0.f, 0.f);
        float e = 0.f;
        if (gl < L_SEQ) {
            Bv = *(const float4*)(tl + (size_t)gl * 12);
            e = exp2f(csp[c * 4 + h] - acsp[(size_t)gl * 4 + h]) * dtbp[(size_t)gl * 4 + h];
        }
        *(float4*)&coef[l_loc][h * 4] = make_float4(Bv.x * e, Bv.y * e, Bv.z * e, Bv.w * e);
    }
    __syncthreads();
    const int h = tid >> 6;
    f32x4 acc = (f32x4){0.f, 0.f, 0.f, 0.f};
#pragma unroll 4
    for (int j = 0; j < 64; ++j) {
        const int gl = c * 256 + q * 64 + j;
        float xs = 0.f;
        if (gl < L_SEQ) xs = bf2f(zxp[(size_t)gl * 512 + 256 + tid]);
        float4 cf = *(const float4*)&coef[j][h * 4];
        acc[0] += cf.x * xs; acc[1] += cf.y * xs;
        acc[2] += cf.z * xs; acc[3] += cf.w * xs;
    }
    *(f32x4*)(spp + ((size_t)(c * 4 + q) * 256 + tid) * 4) = acc;
}

// ---------------------------------------------------------------------------
// Inter-chunk scan with fused q-reduction (batched: blockIdx.y = path).
// ---------------------------------------------------------------------------
__launch_bounds__(256)
__global__ void chunkscan_k(const float* __restrict__ csum, const float* __restrict__ spart,
                            float* __restrict__ prev)
{
    const int z = blockIdx.y;
    const float* csp = csum + (size_t)z * NCH * 4;
    const float* spp = spart + (size_t)z * NCH * 4096;
    float* prp = prev + (size_t)z * NCH * 1024;

    const int h = blockIdx.x;
    const int tid = threadIdx.x;
    __shared__ float ecs[NCH];
    if (tid < NCH) ecs[tid] = exp2f(csp[tid * 4 + h]);
    __syncthreads();
    float run = 0.f;
#pragma unroll 2
    for (int c = 0; c < NCH; ++c) {
        const float* sp = spp + (size_t)(c * 4) * 1024 + h * 256 + tid;
        float s = sp[0] + sp[1024] + sp[2048] + sp[3072];
        prp[(size_t)c * 1024 + h * 256 + tid] = run;
        run = run * ecs[c] + s;
    }
}

// ---------------------------------------------------------------------------
// MFMA per-chunk output (batched: blockIdx.z = path).
// ---------------------------------------------------------------------------
__launch_bounds__(512, 2)
__global__ void ychunk3_k(const u16* __restrict__ zxb, const float* __restrict__ tail,
                          const float* __restrict__ dtb, const float* __restrict__ acsb,
                          const float* __restrict__ prev, const float* __restrict__ Dv0,
                          const float* __restrict__ Dv1, const int* __restrict__ mor0,
                          const int* __restrict__ mor1, u16* __restrict__ cat)
{
    const int z = blockIdx.z;
    const u16* zxp = zxb + (size_t)z * L_SEQ * 512;
    const float* tl = tail + (size_t)z * L_SEQ * 12;
    const float* dtbp = dtb + (size_t)z * L_SEQ * 4;
    const float* acsp = acsb + (size_t)z * L_SEQ * 4;
    const float* prp = prev + (size_t)z * NCH * 1024;
    const float* Dv = z ? Dv1 : Dv0;
    const int* mor = z ? mor1 : mor0;
    const int catOff = z * 256;

    __shared__ __align__(16) u16 Xt[64 * 256];
    __shared__ __align__(16) u16 Xp[64 * 40];
    __shared__ float4 sBdt[256];
    __shared__ float4 sC[256];
    __shared__ float  sA2[256];

    const int c = blockIdx.x, h = blockIdx.y;
    const int tid = threadIdx.x;
    const int lane = tid & 63, w = tid >> 6;

    {
        const int p = lane;
        const size_t colOff = 256 + h * 64 + p;
#pragma unroll
        for (int jq = 0; jq < 4; ++jq) {
            const int s0 = w * 32 + jq * 8;
            u32 wd[4];
#pragma unroll
            for (int q = 0; q < 4; ++q) {
                int gl0 = c * 256 + s0 + q * 2;
                u32 lo = (gl0     < L_SEQ) ? (u32)zxp[(size_t)gl0 * 512 + colOff] : 0u;
                u32 hi = (gl0 + 1 < L_SEQ) ? (u32)zxp[(size_t)(gl0 + 1) * 512 + colOff] : 0u;
                wd[q] = lo | (hi << 16);
            }
            u32 off = (u32)(p * 512 + s0 * 2) ^ (u32)((p & 15) << 4);
            *(uint4*)((char*)Xt + off) = make_uint4(wd[0], wd[1], wd[2], wd[3]);
        }
    }
    if (tid < 64) {
        float4 pv = *(const float4*)(prp + (size_t)c * 1024 + h * 256 + tid * 4);
        u32 w0 = cvtpk(pv.x, pv.y), w1 = cvtpk(pv.z, pv.w);
        uint4* row = (uint4*)((char*)Xp + tid * 80);
        row[0] = make_uint4(w0, w1, 0u, 0u);
        row[1] = make_uint4(0u, 0u, 0u, 0u);
        row[2] = make_uint4(0u, 0u, 0u, 0u);
        row[3] = make_uint4(0u, 0u, 0u, 0u);
    }
    if (tid < 256) {
        const int s = tid, gl = c * 256 + s;
        if (gl < L_SEQ) {
            const float* tr = tl + (size_t)gl * 12;
            float4 B4 = *(const float4*)tr;
            float4 C4v = *(const float4*)(tr + 4);
            float dt = dtbp[(size_t)gl * 4 + h];
            sBdt[s] = make_float4(B4.x * dt, B4.y * dt, B4.z * dt, B4.w * dt);
            sC[s] = C4v;
            sA2[s] = acsp[(size_t)gl * 4 + h];
        } else {
            sBdt[s] = make_float4(0.f, 0.f, 0.f, 0.f);
            sC[s] = make_float4(0.f, 0.f, 0.f, 0.f);
            sA2[s] = 0.f;
        }
    }
    __syncthreads();

    const int rl15 = lane & 15, kg = lane >> 4;
    const int R[2] = {w * 16, 240 - w * 16};
    const float Dh = Dv[h];
    int lrow[2]; float4 C4[2]; float al2[2]; int km[2];
#pragma unroll
    for (int m = 0; m < 2; ++m) {
        lrow[m] = R[m] + rl15;
        C4[m] = sC[lrow[m]];
        al2[m] = sA2[lrow[m]];
        km[m] = R[m] >> 5;
    }

    f32x4 acc[2][4];
#pragma unroll
    for (int m = 0; m < 2; ++m)
#pragma unroll
        for (int n = 0; n < 4; ++n)
            acc[m][n] = (f32x4){0.f, 0.f, 0.f, 0.f};

    const int kmW = km[1];
    for (int ks = 0; ks <= kmW; ++ks) {
        const int s0 = ks * 32 + kg * 8;
        short8 bf[4];
#pragma unroll
        for (int n = 0; n < 4; ++n) {
            int col = n * 16 + rl15;
            u32 off = (u32)(col * 512 + ks * 64 + kg * 16) ^ (u32)((col & 15) << 4);
            bf[n] = *(const short8*)((const char*)Xt + off);
        }
        float4 Bv[8]; float a2[8];
#pragma unroll
        for (int j = 0; j < 8; ++j) { Bv[j] = sBdt[s0 + j]; a2[j] = sA2[s0 + j]; }
#pragma unroll
        for (int m = 0; m < 2; ++m) {
            if (ks > km[m]) continue;
            float vv[8];
            if (ks < km[m]) {
#pragma unroll
                for (int j = 0; j < 8; ++j) {
                    float dot = C4[m].x * Bv[j].x + C4[m].y * Bv[j].y
                              + C4[m].z * Bv[j].z + C4[m].w * Bv[j].w;
                    vv[j] = dot * exp2f(al2[m] - a2[j]);
                }
            } else {
#pragma unroll
                for (int j = 0; j < 8; ++j) {
                    int s = s0 + j;
                    float dot = C4[m].x * Bv[j].x + C4[m].y * Bv[j].y
                              + C4[m].z * Bv[j].z + C4[m].w * Bv[j].w;
                    float v = dot * exp2f(al2[m] - a2[j]);
                    v = (s <= lrow[m]) ? v : 0.f;
                    vv[j] = (s == lrow[m]) ? v + Dh : v;
                }
            }
            union { u32 wd[4]; short8 v; } aw;
#pragma unroll
            for (int q = 0; q < 4; ++q) aw.wd[q] = cvtpk(vv[2 * q], vv[2 * q + 1]);
#pragma unroll
            for (int n = 0; n < 4; ++n)
                acc[m][n] = __builtin_amdgcn_mfma_f32_16x16x32_bf16(aw.v, bf[n], acc[m][n], 0, 0, 0);
        }
    }
    {
        short8 bp[4];
#pragma unroll
        for (int n = 0; n < 4; ++n) {
            int col = n * 16 + rl15;
            bp[n] = *(const short8*)((const char*)Xp + col * 80 + kg * 16);
        }
#pragma unroll
        for (int m = 0; m < 2; ++m) {
            float ea = exp2f(al2[m]);
            union { u32 wd[4]; short8 v; } aw;
            aw.wd[0] = (kg == 0) ? cvtpk(ea * C4[m].x, ea * C4[m].y) : 0u;
            aw.wd[1] = (kg == 0) ? cvtpk(ea * C4[m].z, ea * C4[m].w) : 0u;
            aw.wd[2] = 0u; aw.wd[3] = 0u;
#pragma unroll
            for (int n = 0; n < 4; ++n)
                acc[m][n] = __builtin_amdgcn_mfma_f32_16x16x32_bf16(aw.v, bp[n], acc[m][n], 0, 0, 0);
        }
    }

#pragma unroll
    for (int m = 0; m < 2; ++m) {
#pragma unroll
        for (int r = 0; r < 4; ++r) {
            const int row = R[m] + kg * 4 + r;
            const int gl = c * 256 + row;
            if (gl >= L_SEQ) continue;
            const int pos = mor[gl];
            const size_t zbase = (size_t)gl * 512 + h * 64;
            u16* orow = cat + (size_t)pos * 512 + catOff + h * 64;
#pragma unroll
            for (int n = 0; n < 4; ++n) {
                const int col = n * 16 + rl15;
                float zs = bf2f(zxp[zbase + col]);
                float y = acc[m][n][r] * zs;
                orow[col] = (u16)cvtpk(y, y);
            }
        }
    }
}

// ---------------------------------------------------------------------------
// LayerNorm over channel dim (256).
// ---------------------------------------------------------------------------
__launch_bounds__(256)
__global__ void ln_k(const float* __restrict__ pin, const float* __restrict__ g,
                     const float* __restrict__ b, float* __restrict__ pout)
{
    const int l = blockIdx.x, c = threadIdx.x;
    float v = pin[(size_t)l * 256 + c];
    float s = v, s2 = v * v;
#pragma unroll
    for (int o = 32; o > 0; o >>= 1) { s += __shfl_down(s, o); s2 += __shfl_down(s2, o); }
    __shared__ float ws0[4], ws1[4];
    if ((c & 63) == 0) { ws0[c >> 6] = s; ws1[c >> 6] = s2; }
    __syncthreads();
    float ts = ws0[0] + ws0[1] + ws0[2] + ws0[3];
    float t2 = ws1[0] + ws1[1] + ws1[2] + ws1[3];
    float mu = ts * (1.f / 256.f);
    float var = t2 * (1.f / 256.f) - mu * mu;
    float r = rsqrtf(var + 1e-6f);
    pout[(size_t)l * 256 + c] = (v - mu) * r * g[c] + b[c];
}

// ---------------------------------------------------------------------------
// Transpose (L x 256) -> (256 x L).
// ---------------------------------------------------------------------------
__global__ void transpose_k(const float* __restrict__ pin, float* __restrict__ pout)
{
    __shared__ float t[64][65];
    const int l0 = blockIdx.x * 64, c0 = blockIdx.y * 64;
    const int tx = threadIdx.x, ty = threadIdx.y;
#pragma unroll
    for (int j = 0; j < 16; ++j) {
        int row = ty + j * 4;
        int l = l0 + row;
        t[row][tx] = (l < L_SEQ) ? pin[(size_t)l * 256 + c0 + tx] : 0.f;
    }
    __syncthreads();
#pragma unroll
    for (int j = 0; j < 16; ++j) {
        int crow = ty + j * 4;
        int lcol = l0 + tx;
        if (lcol < L_SEQ) pout[(size_t)(c0 + crow) * L_SEQ + lcol] = t[tx][crow];
    }
}

// ---------------------------------------------------------------------------
extern "C" void kernel_launch(void* const* d_in, const int* in_sizes, int n_in,
                              void* d_out, int out_size, void* d_ws, size_t ws_size,
                              hipStream_t stream)
{
    const float* x      = (const float*)d_in[0];
    const float* W_in0  = (const float*)d_in[1];
    const float* W_in1  = (const float*)d_in[2];
    const float* dt_b0  = (const float*)d_in[3];
    const float* dt_b1  = (const float*)d_in[4];
    const float* A_log0 = (const float*)d_in[5];
    const float* A_log1 = (const float*)d_in[6];
    const float* Dv0    = (const float*)d_in[7];
    const float* Dv1    = (const float*)d_in[8];
    const float* W_out  = (const float*)d_in[9];
    const float* ln_g   = (const float*)d_in[10];
    const float* ln_b   = (const float*)d_in[11];
    const int*   mor0   = (const int*)d_in[12];
    const int*   mor1   = (const int*)d_in[13];
    const int*   inv0   = (const int*)d_in[14];
    const int*   inv1   = (const int*)d_in[15];

    char* ws = (char*)d_ws;
    size_t off = 0;
    auto alloc = [&](size_t bytes) { char* p = ws + off; off += (bytes + 255) & ~(size_t)255; return p; };
    u16*   zxb   = (u16*)  alloc((size_t)2 * L_SEQ * 512 * 2);
    u16*   cat   = (u16*)  alloc((size_t)MPAD * 512 * 2);
    float* tail  = (float*)alloc((size_t)2 * L_SEQ * 12 * 4);
    u16*   xg    = (u16*)  alloc((size_t)2 * MPAD * 256 * 2);
    u16*   wbufI = (u16*)  alloc((size_t)2 * 640 * 256 * 2);
    u16*   wbufO = (u16*)  alloc((size_t)256 * 512 * 2);
    float* dtb   = (float*)alloc((size_t)2 * L_SEQ * 4 * 4);
    float* acsb  = (float*)alloc((size_t)2 * L_SEQ * 4 * 4);
    float* csum  = (float*)alloc((size_t)2 * NCH * 4 * 4);
    float* spart = (float*)alloc((size_t)2 * NCH * 4096 * 4);
    float* prev  = (float*)alloc((size_t)2 * NCH * 1024 * 4);
    float* proj  = (float*)zxb;
    float* lnout = (float*)cat;

    convpad2_k<<<dim3(640, 2), 256, 0, stream>>>(W_in0, W_in1, wbufI, 524, 256, (size_t)640 * 256);
    convpad2_k<<<dim3(256, 1), 256, 0, stream>>>(W_out, W_out, wbufO, 256, 512, 0);
    gather_k<<<dim3(507, 2), 256, 0, stream>>>(x, inv0, inv1, xg);
    zero2_k<<<dim3(112, 2), 256, 0, stream>>>(xg + (size_t)L_SEQ * 256, (size_t)MPAD * 256, 112 * 256);

    // in-proj, both paths, W-stationary, DEPTH-4 ring (3 panels x 86 groups x 2)
    wgemm_k<1, 256, 3, 4><<<dim3(3, 86, 2), 512, 0, stream>>>(
        xg, (size_t)MPAD * 256, wbufI, (size_t)640 * 256, nullptr, zxb, tail);

    prep_k<<<dim3(NCH, 2), 256, 0, stream>>>(tail, dt_b0, dt_b1, A_log0, A_log1, dtb, acsb, csum);
    states_part_k<<<dim3(NCH, 4, 2), 256, 0, stream>>>(zxb, dtb, tail, acsb, csum, spart);
    chunkscan_k<<<dim3(4, 2), 256, 0, stream>>>(csum, spart, prev);
    ychunk3_k<<<dim3(NCH, NH, 2), 512, 0, stream>>>(zxb, tail, dtb, acsb, prev,
                                                    Dv0, Dv1, mor0, mor1, cat);

    zero2_k<<<dim3(224, 1), 256, 0, stream>>>(cat + (size_t)L_SEQ * 512, 0, 112 * 512);
    // out-proj, DEPTH-3 ring (2 panels x 128 groups)
    wgemm_k<0, 512, 2, 3><<<dim3(2, 128, 1), 512, 0, stream>>>(
        cat, 0, wbufO, 0, proj, nullptr, nullptr);

    ln_k<<<L_SEQ, 256, 0, stream>>>(proj, ln_g, ln_b, lnout);
    transpose_k<<<dim3(507, 4), dim3(64, 4), 0, stream>>>(lnout, (float*)d_out);
}

// Round 11
// 292.704 us; speedup vs baseline: 1.9519x; 1.0416x over previous
//
#include <hip/hip_runtime.h>
#include <cstdint>

#define L_SEQ 32400
#define HWSZ  32400
#define MPAD  32512
#define NCH   127
#define NH    4
#define LOG2E 1.4426950408889634f

typedef unsigned short u16;
typedef unsigned int   u32;
typedef __attribute__((ext_vector_type(8))) short short8;
typedef __attribute__((ext_vector_type(4))) float f32x4;

__device__ __forceinline__ float silu_f(float v) {
    float e = __expf(-v);
    return v * __builtin_amdgcn_rcpf(1.f + e);
}
__device__ __forceinline__ float softplus_f(float v) { return v > 20.f ? v : log1pf(__expf(v)); }
__device__ __forceinline__ u16 f2bf(float f) {
    u32 u = __float_as_uint(f);
    u += 0x7FFFu + ((u >> 16) & 1u);
    return (u16)(u >> 16);
}
__device__ __forceinline__ u32 cvtpk(float lo, float hi) {
    u32 r;
    asm("v_cvt_pk_bf16_f32 %0, %1, %2" : "=v"(r) : "v"(lo), "v"(hi));
    return r;
}
__device__ __forceinline__ float bf2f(u32 u) { return __uint_as_float(u << 16); }

// ---------------------------------------------------------------------------
// Transpose x [C][HW] -> xt [pix][C] bf16 (pixel order, no permutation).
// ---------------------------------------------------------------------------
__launch_bounds__(256)
__global__ void xpose_k(const float* __restrict__ x, u16* __restrict__ xt)
{
    __shared__ u16 tile[256][66];
    const int pix0 = blockIdx.x * 64;
    const int tid = threadIdx.x;
    const int pl = tid & 63, cq = tid >> 6;
    const int pix = pix0 + pl;
    const bool pv = pix < HWSZ;
#pragma unroll 4
    for (int j = 0; j < 64; ++j) {
        int c = cq * 64 + j;
        float v = pv ? x[(size_t)c * HWSZ + pix] : 0.f;
        tile[c][pl] = f2bf(v);
    }
    __syncthreads();
    for (int i = 0; i < 64; ++i) {
        int p2 = pix0 + i;
        if (p2 < HWSZ) xt[(size_t)p2 * 256 + tid] = tile[tid][i];
    }
}

__global__ void zero2_k(u16* __restrict__ p, size_t zstride, int n)
{
    int i = blockIdx.x * 256 + threadIdx.x;
    if (i < n) p[(size_t)blockIdx.y * zstride + i] = 0;
}

__global__ void convpad2_k(const float* __restrict__ s0, const float* __restrict__ s1,
                           u16* __restrict__ dst, int rows, int cols, size_t zstride)
{
    const int z = blockIdx.y;
    const float* __restrict__ src = z ? s1 : s0;
    u16* __restrict__ d = dst + (size_t)z * zstride;
    int r = blockIdx.x;
    for (int c = threadIdx.x; c < cols; c += 256)
        d[(size_t)r * cols + c] = (r < rows) ? f2bf(src[(size_t)r * cols + c]) : (u16)0;
}

// ---------------------------------------------------------------------------
// W-stationary streaming GEMM v2 ("wsgemm"):
//  - 8 waves, wave wn owns cols c0 + (wn*NFRAG+f)*16; W frags in regs
//    (NFRAG sized so wf = 64 VGPR; launch_bounds(512,4) caps 128 -> no spill)
//  - M streamed in 32-row tiles through ONE 32xK LDS buffer, reg-staged:
//    loads->regs at top of iter, compute, barrier, ds_write (compiler
//    inserts exact vmcnt), barrier.  No hand vmcnt -> store-proof.
//  - XCD-chunked bijective block remap (m204): each XCD gets a contiguous
//    t-range x all panels -> A row-tiles fetched ~once into its L2.
// MODE 1: in-proj, A=xt (pixel order), N=1280 (2 paths); silu/split epilogue.
// MODE 0: out-proj, bf16 output.
// ---------------------------------------------------------------------------
template<int MODE, int K, int NFRAG, int NPANEL, int G>
__launch_bounds__(512, 4)
__global__ void wsgemm_k(const u16* __restrict__ A, const u16* __restrict__ W,
                         u16* __restrict__ outB, u16* __restrict__ zxb,
                         float* __restrict__ tail)
{
    constexpr int KS = K / 32;
    constexpr int SLOTS = K / 8;
    constexpr int LOADS = (32 * SLOTS) / 512;
    __shared__ u16 As[32 * K];

    // bijective XCD-chunk remap (m204)
    const int nwg = NPANEL * G;
    const int orig = blockIdx.x;
    const int xcd = orig & 7;
    const int q = nwg >> 3, r = nwg & 7;
    const int wgid = (xcd < r ? xcd * (q + 1) : r * (q + 1) + (xcd - r) * q) + (orig >> 3);
    const int panel = wgid % NPANEL;
    const int t0 = wgid / NPANEL;

    const int tid = threadIdx.x;
    const int lane = tid & 63, wn = tid >> 6;
    const int rl15 = lane & 15, kg = lane >> 4;
    const int c0 = panel * (NFRAG * 128);
    const int NT = MPAD / 32;

    // ---- W fragments -> registers (once) ----
    short8 wf[NFRAG][KS];
#pragma unroll
    for (int f = 0; f < NFRAG; ++f) {
        const int row = c0 + (wn * NFRAG + f) * 16 + rl15;
#pragma unroll
        for (int ks = 0; ks < KS; ++ks)
            wf[f][ks] = *(const short8*)(W + (size_t)row * K + ks * 32 + kg * 8);
    }

    auto loadregs = [&](int t, uint4* st) {
        const u16* src = A + (size_t)t * 32 * K;
#pragma unroll
        for (int i = 0; i < LOADS; ++i) {
            int ch = i * 512 + tid;
            int row = ch / SLOTS, sl = ch % SLOTS;
            st[i] = *(const uint4*)(src + (size_t)row * K + sl * 8);
        }
    };
    auto dswrite = [&](uint4* st) {
#pragma unroll
        for (int i = 0; i < LOADS; ++i) {
            int ch = i * 512 + tid;
            int row = ch / SLOTS, sl = ch % SLOTS;
            *(uint4*)((char*)As + row * (K * 2) + ((sl ^ (row & 7)) * 16)) = st[i];
        }
    };

    uint4 st[LOADS];
    loadregs(t0, st);
    dswrite(st);
    asm volatile("s_waitcnt lgkmcnt(0)" ::: "memory");
    __builtin_amdgcn_sched_barrier(0);
    __builtin_amdgcn_s_barrier();

    for (int t = t0; t < NT; t += G) {
        const bool hn = (t + G) < NT;
        if (hn) loadregs(t + G, st);

        f32x4 acc[2][NFRAG];
#pragma unroll
        for (int rr = 0; rr < 2; ++rr)
#pragma unroll
            for (int f = 0; f < NFRAG; ++f)
                acc[rr][f] = (f32x4){0.f, 0.f, 0.f, 0.f};

        __builtin_amdgcn_s_setprio(1);
#pragma unroll
        for (int ks = 0; ks < KS; ++ks) {
            short8 a[2];
#pragma unroll
            for (int rr = 0; rr < 2; ++rr) {
                int row = rr * 16 + rl15;
                int sw = (ks * 4 + kg) ^ (row & 7);
                a[rr] = *(const short8*)((const char*)As + row * (K * 2) + sw * 16);
            }
#pragma unroll
            for (int rr = 0; rr < 2; ++rr)
#pragma unroll
                for (int f = 0; f < NFRAG; ++f)
                    acc[rr][f] = __builtin_amdgcn_mfma_f32_16x16x32_bf16(a[rr], wf[f][ks], acc[rr][f], 0, 0, 0);
        }
        __builtin_amdgcn_s_setprio(0);
        __builtin_amdgcn_s_barrier();
        if (hn) {
            dswrite(st);                      // compiler inserts exact vmcnt wait
            asm volatile("s_waitcnt lgkmcnt(0)" ::: "memory");
            __builtin_amdgcn_sched_barrier(0);
        }
        __builtin_amdgcn_s_barrier();

        // ---- epilogue for tile t (overlaps next iter's loads/compute) ----
#pragma unroll
        for (int rr = 0; rr < 2; ++rr) {
#pragma unroll
            for (int f = 0; f < NFRAG; ++f) {
                const int col = c0 + (wn * NFRAG + f) * 16 + rl15;
#pragma unroll
                for (int ri = 0; ri < 4; ++ri) {
                    const int gl = t * 32 + rr * 16 + kg * 4 + ri;
                    if (gl >= L_SEQ) continue;
                    float v = acc[rr][f][ri];
                    if (MODE == 0) {
                        outB[(size_t)gl * 256 + col] = (u16)cvtpk(v, v);
                    } else {
                        int zp = (col >= 640) ? 1 : 0;
                        int c6 = col - zp * 640;
                        if (c6 < 512) {
                            float s = silu_f(v);
                            zxb[(size_t)zp * L_SEQ * 512 + (size_t)gl * 512 + c6] = (u16)cvtpk(s, s);
                        } else if (c6 < 520) {
                            tail[(size_t)zp * L_SEQ * 12 + (size_t)gl * 12 + (c6 - 512)] = silu_f(v);
                        } else if (c6 < 524) {
                            tail[(size_t)zp * L_SEQ * 12 + (size_t)gl * 12 + (c6 - 512)] = v;
                        }
                    }
                }
            }
        }
    }
}

// ---------------------------------------------------------------------------
// Per-chunk prep; tail rows gathered via morton (pixel-order tail).
// ---------------------------------------------------------------------------
__launch_bounds__(256)
__global__ void prep_k(const float* __restrict__ tail, const float* __restrict__ db0,
                       const float* __restrict__ db1, const float* __restrict__ al0,
                       const float* __restrict__ al1, const int* __restrict__ mor0,
                       const int* __restrict__ mor1, float* __restrict__ dtb,
                       float* __restrict__ acsb, float* __restrict__ csum)
{
    const int z = blockIdx.y;
    const float* dt_bias = z ? db1 : db0;
    const float* A_log = z ? al1 : al0;
    const int* mor = z ? mor1 : mor0;
    const float* tl = tail + (size_t)z * L_SEQ * 12;
    float* dtbp = dtb + (size_t)z * L_SEQ * 4;
    float* acsp = acsb + (size_t)z * L_SEQ * 4;
    float* csp = csum + (size_t)z * NCH * 4;

    const int c = blockIdx.x;
    const int l = threadIdx.x;
    const int lane = l & 63, w = l >> 6;
    const int gl = c * 256 + l;
    const bool valid = gl < L_SEQ;
    float v[NH] = {0.f, 0.f, 0.f, 0.f};
    if (valid) {
        const int pos = mor[gl];
        float4 dv = *(const float4*)(tl + (size_t)pos * 12 + 8);
        const float* dp = (const float*)&dv;
#pragma unroll
        for (int h = 0; h < NH; ++h) {
            float dt = softplus_f(dp[h] + dt_bias[h]);
            dtbp[(size_t)gl * 4 + h] = dt;
            v[h] = -__expf(A_log[h]) * LOG2E * dt;
        }
    }
#pragma unroll
    for (int off = 1; off < 64; off <<= 1) {
#pragma unroll
        for (int h = 0; h < NH; ++h) {
            float tt = __shfl_up(v[h], off, 64);
            if (lane >= off) v[h] += tt;
        }
    }
    __shared__ float wsum[4][NH];
    if (lane == 63)
#pragma unroll
        for (int h = 0; h < NH; ++h) wsum[w][h] = v[h];
    __syncthreads();
#pragma unroll
    for (int h = 0; h < NH; ++h) {
        float o = 0.f;
#pragma unroll
        for (int w2 = 0; w2 < 4; ++w2) if (w2 < w) o += wsum[w2][h];
        v[h] += o;
    }
    if (valid)
#pragma unroll
        for (int h = 0; h < NH; ++h) acsp[(size_t)gl * 4 + h] = v[h];
    if (l == 255)
#pragma unroll
        for (int h = 0; h < NH; ++h) csp[c * 4 + h] = v[h];
}

// ---------------------------------------------------------------------------
// Chunk-end states, partial; pixel-order zxb/tail gathered via morton.
// ---------------------------------------------------------------------------
__launch_bounds__(256)
__global__ void states_part_k(const u16* __restrict__ zxb, const float* __restrict__ dtb,
                              const float* __restrict__ tail, const float* __restrict__ acsb,
                              const float* __restrict__ csum, const int* __restrict__ mor0,
                              const int* __restrict__ mor1, float* __restrict__ spart)
{
    const int z = blockIdx.z;
    const u16* zxp = zxb + (size_t)z * L_SEQ * 512;
    const float* dtbp = dtb + (size_t)z * L_SEQ * 4;
    const float* tl = tail + (size_t)z * L_SEQ * 12;
    const float* acsp = acsb + (size_t)z * L_SEQ * 4;
    const float* csp = csum + (size_t)z * NCH * 4;
    const int* mor = z ? mor1 : mor0;
    float* spp = spart + (size_t)z * NCH * 4096;

    __shared__ float coef[64][16];
    __shared__ int posL[64];
    const int c = blockIdx.x, q = blockIdx.y;
    const int tid = threadIdx.x;
    {
        const int l_loc = tid >> 2, h = tid & 3;
        const int gl = c * 256 + q * 64 + l_loc;
        const int pos = (gl < L_SEQ) ? mor[gl] : 0;
        float4 Bv = make_float4(0.f, 0.f, 0.f, 0.f);
        float e = 0.f;
        if (gl < L_SEQ) {
            Bv = *(const float4*)(tl + (size_t)pos * 12);
            e = exp2f(csp[c * 4 + h] - acsp[(size_t)gl * 4 + h]) * dtbp[(size_t)gl * 4 + h];
        }
        *(float4*)&coef[l_loc][h * 4] = make_float4(Bv.x * e, Bv.y * e, Bv.z * e, Bv.w * e);
        if (h == 0) posL[l_loc] = pos;
    }
    __syncthreads();
    const int h = tid >> 6;
    f32x4 acc = (f32x4){0.f, 0.f, 0.f, 0.f};
#pragma unroll 4
    for (int j = 0; j < 64; ++j) {
        const int gl = c * 256 + q * 64 + j;
        float xs = 0.f;
        if (gl < L_SEQ) xs = bf2f(zxp[(size_t)posL[j] * 512 + 256 + tid]);
        float4 cf = *(const float4*)&coef[j][h * 4];
        acc[0] += cf.x * xs; acc[1] += cf.y * xs;
        acc[2] += cf.z * xs; acc[3] += cf.w * xs;
    }
    *(f32x4*)(spp + ((size_t)(c * 4 + q) * 256 + tid) * 4) = acc;
}

// ---------------------------------------------------------------------------
// Inter-chunk scan with fused q-reduction.
// ---------------------------------------------------------------------------
__launch_bounds__(256)
__global__ void chunkscan_k(const float* __restrict__ csum, const float* __restrict__ spart,
                            float* __restrict__ prev)
{
    const int z = blockIdx.y;
    const float* csp = csum + (size_t)z * NCH * 4;
    const float* spp = spart + (size_t)z * NCH * 4096;
    float* prp = prev + (size_t)z * NCH * 1024;

    const int h = blockIdx.x;
    const int tid = threadIdx.x;
    __shared__ float ecs[NCH];
    if (tid < NCH) ecs[tid] = exp2f(csp[tid * 4 + h]);
    __syncthreads();
    float run = 0.f;
#pragma unroll 2
    for (int c = 0; c < NCH; ++c) {
        const float* sp = spp + (size_t)(c * 4) * 1024 + h * 256 + tid;
        float s = sp[0] + sp[1024] + sp[2048] + sp[3072];
        prp[(size_t)c * 1024 + h * 256 + tid] = run;
        run = run * ecs[c] + s;
    }
}

// ---------------------------------------------------------------------------
// MFMA per-chunk output; pixel-order zxb/tail via morL (LDS-staged morton).
// ---------------------------------------------------------------------------
__launch_bounds__(512, 2)
__global__ void ychunk3_k(const u16* __restrict__ zxb, const float* __restrict__ tail,
                          const float* __restrict__ dtb, const float* __restrict__ acsb,
                          const float* __restrict__ prev, const float* __restrict__ Dv0,
                          const float* __restrict__ Dv1, const int* __restrict__ mor0,
                          const int* __restrict__ mor1, u16* __restrict__ cat)
{
    const int z = blockIdx.z;
    const u16* zxp = zxb + (size_t)z * L_SEQ * 512;
    const float* tl = tail + (size_t)z * L_SEQ * 12;
    const float* dtbp = dtb + (size_t)z * L_SEQ * 4;
    const float* acsp = acsb + (size_t)z * L_SEQ * 4;
    const float* prp = prev + (size_t)z * NCH * 1024;
    const float* Dv = z ? Dv1 : Dv0;
    const int* mor = z ? mor1 : mor0;
    const int catOff = z * 256;

    __shared__ __align__(16) u16 Xt[64 * 256];
    __shared__ __align__(16) u16 Xp[64 * 40];
    __shared__ float4 sBdt[256];
    __shared__ float4 sC[256];
    __shared__ float  sA2[256];
    __shared__ int    morL[256];

    const int c = blockIdx.x, h = blockIdx.y;
    const int tid = threadIdx.x;
    const int lane = tid & 63, w = tid >> 6;

    // ---- phase 0: morton + per-s scalars + prev tile ----
    if (tid < 256) {
        const int s = tid, gl = c * 256 + s;
        const int pos = (gl < L_SEQ) ? mor[gl] : 0;
        morL[s] = pos;
        if (gl < L_SEQ) {
            const float* tr = tl + (size_t)pos * 12;
            float4 B4 = *(const float4*)tr;
            float4 C4v = *(const float4*)(tr + 4);
            float dt = dtbp[(size_t)gl * 4 + h];
            sBdt[s] = make_float4(B4.x * dt, B4.y * dt, B4.z * dt, B4.w * dt);
            sC[s] = C4v;
            sA2[s] = acsp[(size_t)gl * 4 + h];
        } else {
            sBdt[s] = make_float4(0.f, 0.f, 0.f, 0.f);
            sC[s] = make_float4(0.f, 0.f, 0.f, 0.f);
            sA2[s] = 0.f;
        }
    } else if (tid < 320) {
        int i = tid - 256;
        float4 pv = *(const float4*)(prp + (size_t)c * 1024 + h * 256 + i * 4);
        u32 w0 = cvtpk(pv.x, pv.y), w1 = cvtpk(pv.z, pv.w);
        uint4* row = (uint4*)((char*)Xp + i * 80);
        row[0] = make_uint4(w0, w1, 0u, 0u);
        row[1] = make_uint4(0u, 0u, 0u, 0u);
        row[2] = make_uint4(0u, 0u, 0u, 0u);
        row[3] = make_uint4(0u, 0u, 0u, 0u);
    }
    __syncthreads();

    // ---- stage X^T via morton rows ----
    {
        const int p = lane;
        const size_t colOff = 256 + h * 64 + p;
#pragma unroll
        for (int jq = 0; jq < 4; ++jq) {
            const int s0 = w * 32 + jq * 8;
            u32 wd[4];
#pragma unroll
            for (int q2 = 0; q2 < 4; ++q2) {
                int sIdx = s0 + q2 * 2;
                int gl0 = c * 256 + sIdx;
                u32 lo = (gl0     < L_SEQ) ? (u32)zxp[(size_t)morL[sIdx] * 512 + colOff] : 0u;
                u32 hi = (gl0 + 1 < L_SEQ) ? (u32)zxp[(size_t)morL[sIdx + 1] * 512 + colOff] : 0u;
                wd[q2] = lo | (hi << 16);
            }
            u32 off = (u32)(p * 512 + s0 * 2) ^ (u32)((p & 15) << 4);
            *(uint4*)((char*)Xt + off) = make_uint4(wd[0], wd[1], wd[2], wd[3]);
        }
    }
    __syncthreads();

    const int rl15 = lane & 15, kg = lane >> 4;
    const int R[2] = {w * 16, 240 - w * 16};
    const float Dh = Dv[h];
    int lrow[2]; float4 C4[2]; float al2[2]; int km[2];
#pragma unroll
    for (int m = 0; m < 2; ++m) {
        lrow[m] = R[m] + rl15;
        C4[m] = sC[lrow[m]];
        al2[m] = sA2[lrow[m]];
        km[m] = R[m] >> 5;
    }

    f32x4 acc[2][4];
#pragma unroll
    for (int m = 0; m < 2; ++m)
#pragma unroll
        for (int n = 0; n < 4; ++n)
            acc[m][n] = (f32x4){0.f, 0.f, 0.f, 0.f};

    const int kmW = km[1];
    for (int ks = 0; ks <= kmW; ++ks) {
        const int s0 = ks * 32 + kg * 8;
        short8 bf[4];
#pragma unroll
        for (int n = 0; n < 4; ++n) {
            int col = n * 16 + rl15;
            u32 off = (u32)(col * 512 + ks * 64 + kg * 16) ^ (u32)((col & 15) << 4);
            bf[n] = *(const short8*)((const char*)Xt + off);
        }
        float4 Bv[8]; float a2[8];
#pragma unroll
        for (int j = 0; j < 8; ++j) { Bv[j] = sBdt[s0 + j]; a2[j] = sA2[s0 + j]; }
#pragma unroll
        for (int m = 0; m < 2; ++m) {
            if (ks > km[m]) continue;
            float vv[8];
            if (ks < km[m]) {
#pragma unroll
                for (int j = 0; j < 8; ++j) {
                    float dot = C4[m].x * Bv[j].x + C4[m].y * Bv[j].y
                              + C4[m].z * Bv[j].z + C4[m].w * Bv[j].w;
                    vv[j] = dot * exp2f(al2[m] - a2[j]);
                }
            } else {
#pragma unroll
                for (int j = 0; j < 8; ++j) {
                    int s = s0 + j;
                    float dot = C4[m].x * Bv[j].x + C4[m].y * Bv[j].y
                              + C4[m].z * Bv[j].z + C4[m].w * Bv[j].w;
                    float v = dot * exp2f(al2[m] - a2[j]);
                    v = (s <= lrow[m]) ? v : 0.f;
                    vv[j] = (s == lrow[m]) ? v + Dh : v;
                }
            }
            union { u32 wd[4]; short8 v; } aw;
#pragma unroll
            for (int q2 = 0; q2 < 4; ++q2) aw.wd[q2] = cvtpk(vv[2 * q2], vv[2 * q2 + 1]);
#pragma unroll
            for (int n = 0; n < 4; ++n)
                acc[m][n] = __builtin_amdgcn_mfma_f32_16x16x32_bf16(aw.v, bf[n], acc[m][n], 0, 0, 0);
        }
    }
    {
        short8 bp[4];
#pragma unroll
        for (int n = 0; n < 4; ++n) {
            int col = n * 16 + rl15;
            bp[n] = *(const short8*)((const char*)Xp + col * 80 + kg * 16);
        }
#pragma unroll
        for (int m = 0; m < 2; ++m) {
            float ea = exp2f(al2[m]);
            union { u32 wd[4]; short8 v; } aw;
            aw.wd[0] = (kg == 0) ? cvtpk(ea * C4[m].x, ea * C4[m].y) : 0u;
            aw.wd[1] = (kg == 0) ? cvtpk(ea * C4[m].z, ea * C4[m].w) : 0u;
            aw.wd[2] = 0u; aw.wd[3] = 0u;
#pragma unroll
            for (int n = 0; n < 4; ++n)
                acc[m][n] = __builtin_amdgcn_mfma_f32_16x16x32_bf16(aw.v, bp[n], acc[m][n], 0, 0, 0);
        }
    }

#pragma unroll
    for (int m = 0; m < 2; ++m) {
#pragma unroll
        for (int r = 0; r < 4; ++r) {
            const int row = R[m] + kg * 4 + r;
            const int gl = c * 256 + row;
            if (gl >= L_SEQ) continue;
            const int pos = morL[row];
            const size_t zbase = (size_t)pos * 512 + h * 64;
            u16* orow = cat + (size_t)pos * 512 + catOff + h * 64;
#pragma unroll
            for (int n = 0; n < 4; ++n) {
                const int col = n * 16 + rl15;
                float zs = bf2f(zxp[zbase + col]);
                float y = acc[m][n][r] * zs;
                orow[col] = (u16)cvtpk(y, y);
            }
        }
    }
}

// ---------------------------------------------------------------------------
// LayerNorm over channel dim (256), bf16 input.
// ---------------------------------------------------------------------------
__launch_bounds__(256)
__global__ void lnb_k(const u16* __restrict__ pin, const float* __restrict__ g,
                      const float* __restrict__ b, float* __restrict__ pout)
{
    const int l = blockIdx.x, c = threadIdx.x;
    float v = bf2f(pin[(size_t)l * 256 + c]);
    float s = v, s2 = v * v;
#pragma unroll
    for (int o = 32; o > 0; o >>= 1) { s += __shfl_down(s, o); s2 += __shfl_down(s2, o); }
    __shared__ float ws0[4], ws1[4];
    if ((c & 63) == 0) { ws0[c >> 6] = s; ws1[c >> 6] = s2; }
    __syncthreads();
    float ts = ws0[0] + ws0[1] + ws0[2] + ws0[3];
    float t2 = ws1[0] + ws1[1] + ws1[2] + ws1[3];
    float mu = ts * (1.f / 256.f);
    float var = t2 * (1.f / 256.f) - mu * mu;
    float r = rsqrtf(var + 1e-6f);
    pout[(size_t)l * 256 + c] = (v - mu) * r * g[c] + b[c];
}

// ---------------------------------------------------------------------------
// Transpose (L x 256) -> (256 x L).
// ---------------------------------------------------------------------------
__global__ void transpose_k(const float* __restrict__ pin, float* __restrict__ pout)
{
    __shared__ float t[64][65];
    const int l0 = blockIdx.x * 64, c0 = blockIdx.y * 64;
    const int tx = threadIdx.x, ty = threadIdx.y;
#pragma unroll
    for (int j = 0; j < 16; ++j) {
        int row = ty + j * 4;
        int l = l0 + row;
        t[row][tx] = (l < L_SEQ) ? pin[(size_t)l * 256 + c0 + tx] : 0.f;
    }
    __syncthreads();
#pragma unroll
    for (int j = 0; j < 16; ++j) {
        int crow = ty + j * 4;
        int lcol = l0 + tx;
        if (lcol < L_SEQ) pout[(size_t)(c0 + crow) * L_SEQ + lcol] = t[tx][crow];
    }
}

// ---------------------------------------------------------------------------
extern "C" void kernel_launch(void* const* d_in, const int* in_sizes, int n_in,
                              void* d_out, int out_size, void* d_ws, size_t ws_size,
                              hipStream_t stream)
{
    const float* x      = (const float*)d_in[0];
    const float* W_in0  = (const float*)d_in[1];
    const float* W_in1  = (const float*)d_in[2];
    const float* dt_b0  = (const float*)d_in[3];
    const float* dt_b1  = (const float*)d_in[4];
    const float* A_log0 = (const float*)d_in[5];
    const float* A_log1 = (const float*)d_in[6];
    const float* Dv0    = (const float*)d_in[7];
    const float* Dv1    = (const float*)d_in[8];
    const float* W_out  = (const float*)d_in[9];
    const float* ln_g   = (const float*)d_in[10];
    const float* ln_b   = (const float*)d_in[11];
    const int*   mor0   = (const int*)d_in[12];
    const int*   mor1   = (const int*)d_in[13];

    char* ws = (char*)d_ws;
    size_t off = 0;
    auto alloc = [&](size_t bytes) { char* p = ws + off; off += (bytes + 255) & ~(size_t)255; return p; };
    u16*   xt    = (u16*)  alloc((size_t)MPAD * 256 * 2);       // pixel-order A; reused as bf16 proj
    u16*   zxb   = (u16*)  alloc((size_t)2 * L_SEQ * 512 * 2);  // pixel-order silu(z)|silu(x)
    u16*   cat   = (u16*)  alloc((size_t)MPAD * 512 * 2);       // reused (f32) as LN out
    float* tail  = (float*)alloc((size_t)2 * L_SEQ * 12 * 4);   // pixel-order
    u16*   wbufI = (u16*)  alloc((size_t)1280 * 256 * 2);
    u16*   wbufO = (u16*)  alloc((size_t)256 * 512 * 2);
    float* dtb   = (float*)alloc((size_t)2 * L_SEQ * 4 * 4);
    float* acsb  = (float*)alloc((size_t)2 * L_SEQ * 4 * 4);
    float* csum  = (float*)alloc((size_t)2 * NCH * 4 * 4);
    float* spart = (float*)alloc((size_t)2 * NCH * 4096 * 4);
    float* prev  = (float*)alloc((size_t)2 * NCH * 1024 * 4);
    u16*   projb = xt;            // xt dead after in-proj GEMM
    float* lnout = (float*)cat;   // cat dead after out-proj

    convpad2_k<<<dim3(640, 2), 256, 0, stream>>>(W_in0, W_in1, wbufI, 524, 256, (size_t)640 * 256);
    convpad2_k<<<dim3(256, 1), 256, 0, stream>>>(W_out, W_out, wbufO, 256, 512, 0);
    xpose_k<<<507, 256, 0, stream>>>(x, xt);
    zero2_k<<<dim3(112, 1), 256, 0, stream>>>(xt + (size_t)L_SEQ * 256, 0, 112 * 256);

    // merged in-proj: M=32512, N=1280 (both paths), K=256
    wsgemm_k<1, 256, 2, 5, 102><<<510, 512, 0, stream>>>(xt, wbufI, nullptr, zxb, tail);

    prep_k<<<dim3(NCH, 2), 256, 0, stream>>>(tail, dt_b0, dt_b1, A_log0, A_log1,
                                             mor0, mor1, dtb, acsb, csum);
    states_part_k<<<dim3(NCH, 4, 2), 256, 0, stream>>>(zxb, dtb, tail, acsb, csum,
                                                       mor0, mor1, spart);
    chunkscan_k<<<dim3(4, 2), 256, 0, stream>>>(csum, spart, prev);
    ychunk3_k<<<dim3(NCH, NH, 2), 512, 0, stream>>>(zxb, tail, dtb, acsb, prev,
                                                    Dv0, Dv1, mor0, mor1, cat);

    zero2_k<<<dim3(224, 1), 256, 0, stream>>>(cat + (size_t)L_SEQ * 512, 0, 112 * 512);
    // out-proj: M=32512, N=256, K=512, bf16 out
    wsgemm_k<0, 512, 1, 2, 256><<<512, 512, 0, stream>>>(cat, wbufO, projb, nullptr, nullptr);

    lnb_k<<<L_SEQ, 256, 0, stream>>>(projb, ln_g, ln_b, lnout);
    transpose_k<<<dim3(507, 4), dim3(64, 4), 0, stream>>>(lnout, (float*)d_out);
}

// Round 12
// 270.151 us; speedup vs baseline: 2.1148x; 1.0835x over previous
//
#include <hip/hip_runtime.h>
#include <cstdint>

#define L_SEQ 32400
#define HWSZ  32400
#define MPAD  32512
#define NCH   127
#define NH    4
#define LOG2E 1.4426950408889634f

typedef unsigned short u16;
typedef unsigned int   u32;
typedef __attribute__((ext_vector_type(8))) short short8;
typedef __attribute__((ext_vector_type(4))) float f32x4;

__device__ __forceinline__ float silu_f(float v) {
    float e = __expf(-v);
    return v * __builtin_amdgcn_rcpf(1.f + e);
}
__device__ __forceinline__ float softplus_f(float v) { return v > 20.f ? v : log1pf(__expf(v)); }
__device__ __forceinline__ u16 f2bf(float f) {
    u32 u = __float_as_uint(f);
    u += 0x7FFFu + ((u >> 16) & 1u);
    return (u16)(u >> 16);
}
__device__ __forceinline__ u32 cvtpk(float lo, float hi) {
    u32 r;
    asm("v_cvt_pk_bf16_f32 %0, %1, %2" : "=v"(r) : "v"(lo), "v"(hi));
    return r;
}
__device__ __forceinline__ float bf2f(u32 u) { return __uint_as_float(u << 16); }

// ---------------------------------------------------------------------------
// Transpose x [C][HW] -> xt [pix][C] bf16.
// ---------------------------------------------------------------------------
__launch_bounds__(256)
__global__ void xpose_k(const float* __restrict__ x, u16* __restrict__ xt)
{
    __shared__ u16 tile[256][66];
    const int pix0 = blockIdx.x * 64;
    const int tid = threadIdx.x;
    const int pl = tid & 63, cq = tid >> 6;
    const int pix = pix0 + pl;
    const bool pv = pix < HWSZ;
#pragma unroll 4
    for (int j = 0; j < 64; ++j) {
        int c = cq * 64 + j;
        float v = pv ? x[(size_t)c * HWSZ + pix] : 0.f;
        tile[c][pl] = f2bf(v);
    }
    __syncthreads();
    for (int i = 0; i < 64; ++i) {
        int p2 = pix0 + i;
        if (p2 < HWSZ) xt[(size_t)p2 * 256 + tid] = tile[tid][i];
    }
}

__global__ void zero2_k(u16* __restrict__ p, size_t zstride, int n)
{
    int i = blockIdx.x * 256 + threadIdx.x;
    if (i < n) p[(size_t)blockIdx.y * zstride + i] = 0;
}

__global__ void convpad2_k(const float* __restrict__ s0, const float* __restrict__ s1,
                           u16* __restrict__ dst, int rows, int cols, size_t zstride)
{
    const int z = blockIdx.y;
    const float* __restrict__ src = z ? s1 : s0;
    u16* __restrict__ d = dst + (size_t)z * zstride;
    int r = blockIdx.x;
    for (int c = threadIdx.x; c < cols; c += 256)
        d[(size_t)r * cols + c] = (r < rows) ? f2bf(src[(size_t)r * cols + c]) : (u16)0;
}

// ---------------------------------------------------------------------------
// W-stationary streaming GEMM (unchanged from round 10).
// ---------------------------------------------------------------------------
template<int MODE, int K, int NFRAG, int NPANEL, int G>
__launch_bounds__(512, 4)
__global__ void wsgemm_k(const u16* __restrict__ A, const u16* __restrict__ W,
                         u16* __restrict__ outB, u16* __restrict__ zxb,
                         float* __restrict__ tail)
{
    constexpr int KS = K / 32;
    constexpr int SLOTS = K / 8;
    constexpr int LOADS = (32 * SLOTS) / 512;
    __shared__ u16 As[32 * K];

    const int nwg = NPANEL * G;
    const int orig = blockIdx.x;
    const int xcd = orig & 7;
    const int q = nwg >> 3, r = nwg & 7;
    const int wgid = (xcd < r ? xcd * (q + 1) : r * (q + 1) + (xcd - r) * q) + (orig >> 3);
    const int panel = wgid % NPANEL;
    const int t0 = wgid / NPANEL;

    const int tid = threadIdx.x;
    const int lane = tid & 63, wn = tid >> 6;
    const int rl15 = lane & 15, kg = lane >> 4;
    const int c0 = panel * (NFRAG * 128);
    const int NT = MPAD / 32;

    short8 wf[NFRAG][KS];
#pragma unroll
    for (int f = 0; f < NFRAG; ++f) {
        const int row = c0 + (wn * NFRAG + f) * 16 + rl15;
#pragma unroll
        for (int ks = 0; ks < KS; ++ks)
            wf[f][ks] = *(const short8*)(W + (size_t)row * K + ks * 32 + kg * 8);
    }

    auto loadregs = [&](int t, uint4* st) {
        const u16* src = A + (size_t)t * 32 * K;
#pragma unroll
        for (int i = 0; i < LOADS; ++i) {
            int ch = i * 512 + tid;
            int row = ch / SLOTS, sl = ch % SLOTS;
            st[i] = *(const uint4*)(src + (size_t)row * K + sl * 8);
        }
    };
    auto dswrite = [&](uint4* st) {
#pragma unroll
        for (int i = 0; i < LOADS; ++i) {
            int ch = i * 512 + tid;
            int row = ch / SLOTS, sl = ch % SLOTS;
            *(uint4*)((char*)As + row * (K * 2) + ((sl ^ (row & 7)) * 16)) = st[i];
        }
    };

    uint4 st[LOADS];
    loadregs(t0, st);
    dswrite(st);
    asm volatile("s_waitcnt lgkmcnt(0)" ::: "memory");
    __builtin_amdgcn_sched_barrier(0);
    __builtin_amdgcn_s_barrier();

    for (int t = t0; t < NT; t += G) {
        const bool hn = (t + G) < NT;
        if (hn) loadregs(t + G, st);

        f32x4 acc[2][NFRAG];
#pragma unroll
        for (int rr = 0; rr < 2; ++rr)
#pragma unroll
            for (int f = 0; f < NFRAG; ++f)
                acc[rr][f] = (f32x4){0.f, 0.f, 0.f, 0.f};

        __builtin_amdgcn_s_setprio(1);
#pragma unroll
        for (int ks = 0; ks < KS; ++ks) {
            short8 a[2];
#pragma unroll
            for (int rr = 0; rr < 2; ++rr) {
                int row = rr * 16 + rl15;
                int sw = (ks * 4 + kg) ^ (row & 7);
                a[rr] = *(const short8*)((const char*)As + row * (K * 2) + sw * 16);
            }
#pragma unroll
            for (int rr = 0; rr < 2; ++rr)
#pragma unroll
                for (int f = 0; f < NFRAG; ++f)
                    acc[rr][f] = __builtin_amdgcn_mfma_f32_16x16x32_bf16(a[rr], wf[f][ks], acc[rr][f], 0, 0, 0);
        }
        __builtin_amdgcn_s_setprio(0);
        __builtin_amdgcn_s_barrier();
        if (hn) {
            dswrite(st);
            asm volatile("s_waitcnt lgkmcnt(0)" ::: "memory");
            __builtin_amdgcn_sched_barrier(0);
        }
        __builtin_amdgcn_s_barrier();

#pragma unroll
        for (int rr = 0; rr < 2; ++rr) {
#pragma unroll
            for (int f = 0; f < NFRAG; ++f) {
                const int col = c0 + (wn * NFRAG + f) * 16 + rl15;
#pragma unroll
                for (int ri = 0; ri < 4; ++ri) {
                    const int gl = t * 32 + rr * 16 + kg * 4 + ri;
                    if (gl >= L_SEQ) continue;
                    float v = acc[rr][f][ri];
                    if (MODE == 0) {
                        outB[(size_t)gl * 256 + col] = (u16)cvtpk(v, v);
                    } else {
                        int zp = (col >= 640) ? 1 : 0;
                        int c6 = col - zp * 640;
                        if (c6 < 512) {
                            float s = silu_f(v);
                            zxb[(size_t)zp * L_SEQ * 512 + (size_t)gl * 512 + c6] = (u16)cvtpk(s, s);
                        } else if (c6 < 520) {
                            tail[(size_t)zp * L_SEQ * 12 + (size_t)gl * 12 + (c6 - 512)] = silu_f(v);
                        } else if (c6 < 524) {
                            tail[(size_t)zp * L_SEQ * 12 + (size_t)gl * 12 + (c6 - 512)] = v;
                        }
                    }
                }
            }
        }
    }
}

// ---------------------------------------------------------------------------
// Per-chunk prep (unchanged).
// ---------------------------------------------------------------------------
__launch_bounds__(256)
__global__ void prep_k(const float* __restrict__ tail, const float* __restrict__ db0,
                       const float* __restrict__ db1, const float* __restrict__ al0,
                       const float* __restrict__ al1, const int* __restrict__ mor0,
                       const int* __restrict__ mor1, float* __restrict__ dtb,
                       float* __restrict__ acsb, float* __restrict__ csum)
{
    const int z = blockIdx.y;
    const float* dt_bias = z ? db1 : db0;
    const float* A_log = z ? al1 : al0;
    const int* mor = z ? mor1 : mor0;
    const float* tl = tail + (size_t)z * L_SEQ * 12;
    float* dtbp = dtb + (size_t)z * L_SEQ * 4;
    float* acsp = acsb + (size_t)z * L_SEQ * 4;
    float* csp = csum + (size_t)z * NCH * 4;

    const int c = blockIdx.x;
    const int l = threadIdx.x;
    const int lane = l & 63, w = l >> 6;
    const int gl = c * 256 + l;
    const bool valid = gl < L_SEQ;
    float v[NH] = {0.f, 0.f, 0.f, 0.f};
    if (valid) {
        const int pos = mor[gl];
        float4 dv = *(const float4*)(tl + (size_t)pos * 12 + 8);
        const float* dp = (const float*)&dv;
#pragma unroll
        for (int h = 0; h < NH; ++h) {
            float dt = softplus_f(dp[h] + dt_bias[h]);
            dtbp[(size_t)gl * 4 + h] = dt;
            v[h] = -__expf(A_log[h]) * LOG2E * dt;
        }
    }
#pragma unroll
    for (int off = 1; off < 64; off <<= 1) {
#pragma unroll
        for (int h = 0; h < NH; ++h) {
            float tt = __shfl_up(v[h], off, 64);
            if (lane >= off) v[h] += tt;
        }
    }
    __shared__ float wsum[4][NH];
    if (lane == 63)
#pragma unroll
        for (int h = 0; h < NH; ++h) wsum[w][h] = v[h];
    __syncthreads();
#pragma unroll
    for (int h = 0; h < NH; ++h) {
        float o = 0.f;
#pragma unroll
        for (int w2 = 0; w2 < 4; ++w2) if (w2 < w) o += wsum[w2][h];
        v[h] += o;
    }
    if (valid)
#pragma unroll
        for (int h = 0; h < NH; ++h) acsp[(size_t)gl * 4 + h] = v[h];
    if (l == 255)
#pragma unroll
        for (int h = 0; h < NH; ++h) csp[c * 4 + h] = v[h];
}

// ---------------------------------------------------------------------------
// Chunk-end states, partial (unchanged).
// ---------------------------------------------------------------------------
__launch_bounds__(256)
__global__ void states_part_k(const u16* __restrict__ zxb, const float* __restrict__ dtb,
                              const float* __restrict__ tail, const float* __restrict__ acsb,
                              const float* __restrict__ csum, const int* __restrict__ mor0,
                              const int* __restrict__ mor1, float* __restrict__ spart)
{
    const int z = blockIdx.z;
    const u16* zxp = zxb + (size_t)z * L_SEQ * 512;
    const float* dtbp = dtb + (size_t)z * L_SEQ * 4;
    const float* tl = tail + (size_t)z * L_SEQ * 12;
    const float* acsp = acsb + (size_t)z * L_SEQ * 4;
    const float* csp = csum + (size_t)z * NCH * 4;
    const int* mor = z ? mor1 : mor0;
    float* spp = spart + (size_t)z * NCH * 4096;

    __shared__ float coef[64][16];
    __shared__ int posL[64];
    const int c = blockIdx.x, q = blockIdx.y;
    const int tid = threadIdx.x;
    {
        const int l_loc = tid >> 2, h = tid & 3;
        const int gl = c * 256 + q * 64 + l_loc;
        const int pos = (gl < L_SEQ) ? mor[gl] : 0;
        float4 Bv = make_float4(0.f, 0.f, 0.f, 0.f);
        float e = 0.f;
        if (gl < L_SEQ) {
            Bv = *(const float4*)(tl + (size_t)pos * 12);
            e = exp2f(csp[c * 4 + h] - acsp[(size_t)gl * 4 + h]) * dtbp[(size_t)gl * 4 + h];
        }
        *(float4*)&coef[l_loc][h * 4] = make_float4(Bv.x * e, Bv.y * e, Bv.z * e, Bv.w * e);
        if (h == 0) posL[l_loc] = pos;
    }
    __syncthreads();
    const int h = tid >> 6;
    f32x4 acc = (f32x4){0.f, 0.f, 0.f, 0.f};
#pragma unroll 4
    for (int j = 0; j < 64; ++j) {
        const int gl = c * 256 + q * 64 + j;
        float xs = 0.f;
        if (gl < L_SEQ) xs = bf2f(zxp[(size_t)posL[j] * 512 + 256 + tid]);
        float4 cf = *(const float4*)&coef[j][h * 4];
        acc[0] += cf.x * xs; acc[1] += cf.y * xs;
        acc[2] += cf.z * xs; acc[3] += cf.w * xs;
    }
    *(f32x4*)(spp + ((size_t)(c * 4 + q) * 256 + tid) * 4) = acc;
}

// ---------------------------------------------------------------------------
// Inter-chunk scan (unchanged).
// ---------------------------------------------------------------------------
__launch_bounds__(256)
__global__ void chunkscan_k(const float* __restrict__ csum, const float* __restrict__ spart,
                            float* __restrict__ prev)
{
    const int z = blockIdx.y;
    const float* csp = csum + (size_t)z * NCH * 4;
    const float* spp = spart + (size_t)z * NCH * 4096;
    float* prp = prev + (size_t)z * NCH * 1024;

    const int h = blockIdx.x;
    const int tid = threadIdx.x;
    __shared__ float ecs[NCH];
    if (tid < NCH) ecs[tid] = exp2f(csp[tid * 4 + h]);
    __syncthreads();
    float run = 0.f;
#pragma unroll 2
    for (int c = 0; c < NCH; ++c) {
        const float* sp = spp + (size_t)(c * 4) * 1024 + h * 256 + tid;
        float s = sp[0] + sp[1024] + sp[2048] + sp[3072];
        prp[(size_t)c * 1024 + h * 256 + tid] = run;
        run = run * ecs[c] + s;
    }
}

// ---------------------------------------------------------------------------
// MFMA per-chunk output v4: 16 waves (1024 thr), ONE row-frag per wave
// (R = w*16, km = w>>1): shorter per-wave critical path, natural
// compute/epilogue phase diversity, 16 resident waves/CU.
// ---------------------------------------------------------------------------
__launch_bounds__(1024, 4)
__global__ void ychunk4_k(const u16* __restrict__ zxb, const float* __restrict__ tail,
                          const float* __restrict__ dtb, const float* __restrict__ acsb,
                          const float* __restrict__ prev, const float* __restrict__ Dv0,
                          const float* __restrict__ Dv1, const int* __restrict__ mor0,
                          const int* __restrict__ mor1, u16* __restrict__ cat)
{
    const int z = blockIdx.z;
    const u16* zxp = zxb + (size_t)z * L_SEQ * 512;
    const float* tl = tail + (size_t)z * L_SEQ * 12;
    const float* dtbp = dtb + (size_t)z * L_SEQ * 4;
    const float* acsp = acsb + (size_t)z * L_SEQ * 4;
    const float* prp = prev + (size_t)z * NCH * 1024;
    const float* Dv = z ? Dv1 : Dv0;
    const int* mor = z ? mor1 : mor0;
    const int catOff = z * 256;

    __shared__ __align__(16) u16 Xt[64 * 256];
    __shared__ __align__(16) u16 Xp[64 * 40];
    __shared__ float4 sBdt[256];
    __shared__ float4 sC[256];
    __shared__ float  sA2[256];
    __shared__ int    morL[256];

    const int c = blockIdx.x, h = blockIdx.y;
    const int tid = threadIdx.x;
    const int lane = tid & 63, w = tid >> 6;     // w = 0..15

    // ---- phase 0: morton + per-s scalars + prev tile ----
    if (tid < 256) {
        const int s = tid, gl = c * 256 + s;
        const int pos = (gl < L_SEQ) ? mor[gl] : 0;
        morL[s] = pos;
        if (gl < L_SEQ) {
            const float* tr = tl + (size_t)pos * 12;
            float4 B4 = *(const float4*)tr;
            float4 C4v = *(const float4*)(tr + 4);
            float dt = dtbp[(size_t)gl * 4 + h];
            sBdt[s] = make_float4(B4.x * dt, B4.y * dt, B4.z * dt, B4.w * dt);
            sC[s] = C4v;
            sA2[s] = acsp[(size_t)gl * 4 + h];
        } else {
            sBdt[s] = make_float4(0.f, 0.f, 0.f, 0.f);
            sC[s] = make_float4(0.f, 0.f, 0.f, 0.f);
            sA2[s] = 0.f;
        }
    } else if (tid < 320) {
        int i = tid - 256;
        float4 pv = *(const float4*)(prp + (size_t)c * 1024 + h * 256 + i * 4);
        u32 w0 = cvtpk(pv.x, pv.y), w1 = cvtpk(pv.z, pv.w);
        uint4* row = (uint4*)((char*)Xp + i * 80);
        row[0] = make_uint4(w0, w1, 0u, 0u);
        row[1] = make_uint4(0u, 0u, 0u, 0u);
        row[2] = make_uint4(0u, 0u, 0u, 0u);
        row[3] = make_uint4(0u, 0u, 0u, 0u);
    }
    __syncthreads();

    // ---- stage X^T: wave w covers s in [w*16, w*16+16), p = lane ----
    {
        const int p = lane;
        const size_t colOff = 256 + h * 64 + p;
#pragma unroll
        for (int jq = 0; jq < 2; ++jq) {
            const int s0 = w * 16 + jq * 8;
            u32 wd[4];
#pragma unroll
            for (int q2 = 0; q2 < 4; ++q2) {
                int sIdx = s0 + q2 * 2;
                int gl0 = c * 256 + sIdx;
                u32 lo = (gl0     < L_SEQ) ? (u32)zxp[(size_t)morL[sIdx] * 512 + colOff] : 0u;
                u32 hi = (gl0 + 1 < L_SEQ) ? (u32)zxp[(size_t)morL[sIdx + 1] * 512 + colOff] : 0u;
                wd[q2] = lo | (hi << 16);
            }
            u32 off = (u32)(p * 512 + s0 * 2) ^ (u32)((p & 15) << 4);
            *(uint4*)((char*)Xt + off) = make_uint4(wd[0], wd[1], wd[2], wd[3]);
        }
    }
    __syncthreads();

    const int rl15 = lane & 15, kg = lane >> 4;
    const int R = w * 16;
    const int km = w >> 1;
    const float Dh = Dv[h];
    const int lrow = R + rl15;
    const float4 C4 = sC[lrow];
    const float al2 = sA2[lrow];

    f32x4 acc[4];
#pragma unroll
    for (int n = 0; n < 4; ++n) acc[n] = (f32x4){0.f, 0.f, 0.f, 0.f};

    for (int ks = 0; ks <= km; ++ks) {
        const int s0 = ks * 32 + kg * 8;
        short8 bf[4];
#pragma unroll
        for (int n = 0; n < 4; ++n) {
            int col = n * 16 + rl15;
            u32 off = (u32)(col * 512 + ks * 64 + kg * 16) ^ (u32)((col & 15) << 4);
            bf[n] = *(const short8*)((const char*)Xt + off);
        }
        float4 Bv[8]; float a2[8];
#pragma unroll
        for (int j = 0; j < 8; ++j) { Bv[j] = sBdt[s0 + j]; a2[j] = sA2[s0 + j]; }
        float vv[8];
        if (ks < km) {
#pragma unroll
            for (int j = 0; j < 8; ++j) {
                float dot = C4.x * Bv[j].x + C4.y * Bv[j].y
                          + C4.z * Bv[j].z + C4.w * Bv[j].w;
                vv[j] = dot * exp2f(al2 - a2[j]);
            }
        } else {
#pragma unroll
            for (int j = 0; j < 8; ++j) {
                int s = s0 + j;
                float dot = C4.x * Bv[j].x + C4.y * Bv[j].y
                          + C4.z * Bv[j].z + C4.w * Bv[j].w;
                float v = dot * exp2f(al2 - a2[j]);
                v = (s <= lrow) ? v : 0.f;
                vv[j] = (s == lrow) ? v + Dh : v;
            }
        }
        union { u32 wd[4]; short8 v; } aw;
#pragma unroll
        for (int q2 = 0; q2 < 4; ++q2) aw.wd[q2] = cvtpk(vv[2 * q2], vv[2 * q2 + 1]);
#pragma unroll
        for (int n = 0; n < 4; ++n)
            acc[n] = __builtin_amdgcn_mfma_f32_16x16x32_bf16(aw.v, bf[n], acc[n], 0, 0, 0);
    }
    // ---- prev contribution as one extra MFMA k-step ----
    {
        short8 bp[4];
#pragma unroll
        for (int n = 0; n < 4; ++n) {
            int col = n * 16 + rl15;
            bp[n] = *(const short8*)((const char*)Xp + col * 80 + kg * 16);
        }
        float ea = exp2f(al2);
        union { u32 wd[4]; short8 v; } aw;
        aw.wd[0] = (kg == 0) ? cvtpk(ea * C4.x, ea * C4.y) : 0u;
        aw.wd[1] = (kg == 0) ? cvtpk(ea * C4.z, ea * C4.w) : 0u;
        aw.wd[2] = 0u; aw.wd[3] = 0u;
#pragma unroll
        for (int n = 0; n < 4; ++n)
            acc[n] = __builtin_amdgcn_mfma_f32_16x16x32_bf16(aw.v, bp[n], acc[n], 0, 0, 0);
    }

    // ---- epilogue: gate with pre-silu'd z, scatter bf16 ----
#pragma unroll
    for (int r = 0; r < 4; ++r) {
        const int row = R + kg * 4 + r;
        const int gl = c * 256 + row;
        if (gl >= L_SEQ) continue;
        const int pos = morL[row];
        const size_t zbase = (size_t)pos * 512 + h * 64;
        u16* orow = cat + (size_t)pos * 512 + catOff + h * 64;
#pragma unroll
        for (int n = 0; n < 4; ++n) {
            const int col = n * 16 + rl15;
            float zs = bf2f(zxp[zbase + col]);
            float y = acc[n][r] * zs;
            orow[col] = (u16)cvtpk(y, y);
        }
    }
}

// ---------------------------------------------------------------------------
// Fused LayerNorm + transpose: projb [l][256] bf16 -> out [256][HW] f32.
// Block = 64 pixels; 4 waves x 16 rows; LN via 64-lane shuffle reduce;
// phase 2 writes contiguous 256B per thread.
// ---------------------------------------------------------------------------
__launch_bounds__(256)
__global__ void lntr_k(const u16* __restrict__ projb, const float* __restrict__ g,
                       const float* __restrict__ b, float* __restrict__ out)
{
    __shared__ float tile[64][257];
    const int l0 = blockIdx.x * 64;
    const int tid = threadIdx.x;
    const int lane = tid & 63, w = tid >> 6;
    const float4 g4 = *(const float4*)(g + lane * 4);
    const float4 b4 = *(const float4*)(b + lane * 4);

    for (int i = 0; i < 16; ++i) {
        const int r = w * 16 + i;
        const int l = l0 + r;
        float v[4] = {0.f, 0.f, 0.f, 0.f};
        if (l < L_SEQ) {
            uint2 pk = *(const uint2*)(projb + (size_t)l * 256 + lane * 4);
            v[0] = bf2f(pk.x & 0xFFFFu); v[1] = bf2f(pk.x >> 16);
            v[2] = bf2f(pk.y & 0xFFFFu); v[3] = bf2f(pk.y >> 16);
        }
        float s = v[0] + v[1] + v[2] + v[3];
        float s2 = v[0] * v[0] + v[1] * v[1] + v[2] * v[2] + v[3] * v[3];
#pragma unroll
        for (int o = 32; o > 0; o >>= 1) { s += __shfl_down(s, o); s2 += __shfl_down(s2, o); }
        s = __shfl(s, 0); s2 = __shfl(s2, 0);
        float mu = s * (1.f / 256.f);
        float var = s2 * (1.f / 256.f) - mu * mu;
        float rs = rsqrtf(var + 1e-6f);
        tile[r][lane * 4 + 0] = (v[0] - mu) * rs * g4.x + b4.x;
        tile[r][lane * 4 + 1] = (v[1] - mu) * rs * g4.y + b4.y;
        tile[r][lane * 4 + 2] = (v[2] - mu) * rs * g4.z + b4.z;
        tile[r][lane * 4 + 3] = (v[3] - mu) * rs * g4.w + b4.w;
    }
    __syncthreads();
    // phase 2: thread tid = channel; contiguous pixel writes
    const int nv = min(64, HWSZ - l0);
    float* orow = out + (size_t)tid * HWSZ + l0;
    if (nv == 64) {
#pragma unroll
        for (int i0 = 0; i0 < 64; i0 += 4) {
            float4 o = make_float4(tile[i0][tid], tile[i0 + 1][tid],
                                   tile[i0 + 2][tid], tile[i0 + 3][tid]);
            *(float4*)(orow + i0) = o;
        }
    } else {
        for (int i = 0; i < nv; ++i) orow[i] = tile[i][tid];
    }
}

// ---------------------------------------------------------------------------
extern "C" void kernel_launch(void* const* d_in, const int* in_sizes, int n_in,
                              void* d_out, int out_size, void* d_ws, size_t ws_size,
                              hipStream_t stream)
{
    const float* x      = (const float*)d_in[0];
    const float* W_in0  = (const float*)d_in[1];
    const float* W_in1  = (const float*)d_in[2];
    const float* dt_b0  = (const float*)d_in[3];
    const float* dt_b1  = (const float*)d_in[4];
    const float* A_log0 = (const float*)d_in[5];
    const float* A_log1 = (const float*)d_in[6];
    const float* Dv0    = (const float*)d_in[7];
    const float* Dv1    = (const float*)d_in[8];
    const float* W_out  = (const float*)d_in[9];
    const float* ln_g   = (const float*)d_in[10];
    const float* ln_b   = (const float*)d_in[11];
    const int*   mor0   = (const int*)d_in[12];
    const int*   mor1   = (const int*)d_in[13];

    char* ws = (char*)d_ws;
    size_t off = 0;
    auto alloc = [&](size_t bytes) { char* p = ws + off; off += (bytes + 255) & ~(size_t)255; return p; };
    u16*   xt    = (u16*)  alloc((size_t)MPAD * 256 * 2);       // reused as bf16 proj
    u16*   zxb   = (u16*)  alloc((size_t)2 * L_SEQ * 512 * 2);
    u16*   cat   = (u16*)  alloc((size_t)MPAD * 512 * 2);
    float* tail  = (float*)alloc((size_t)2 * L_SEQ * 12 * 4);
    u16*   wbufI = (u16*)  alloc((size_t)1280 * 256 * 2);
    u16*   wbufO = (u16*)  alloc((size_t)256 * 512 * 2);
    float* dtb   = (float*)alloc((size_t)2 * L_SEQ * 4 * 4);
    float* acsb  = (float*)alloc((size_t)2 * L_SEQ * 4 * 4);
    float* csum  = (float*)alloc((size_t)2 * NCH * 4 * 4);
    float* spart = (float*)alloc((size_t)2 * NCH * 4096 * 4);
    float* prev  = (float*)alloc((size_t)2 * NCH * 1024 * 4);
    u16*   projb = xt;

    convpad2_k<<<dim3(640, 2), 256, 0, stream>>>(W_in0, W_in1, wbufI, 524, 256, (size_t)640 * 256);
    convpad2_k<<<dim3(256, 1), 256, 0, stream>>>(W_out, W_out, wbufO, 256, 512, 0);
    xpose_k<<<507, 256, 0, stream>>>(x, xt);
    zero2_k<<<dim3(112, 1), 256, 0, stream>>>(xt + (size_t)L_SEQ * 256, 0, 112 * 256);

    wsgemm_k<1, 256, 2, 5, 102><<<510, 512, 0, stream>>>(xt, wbufI, nullptr, zxb, tail);

    prep_k<<<dim3(NCH, 2), 256, 0, stream>>>(tail, dt_b0, dt_b1, A_log0, A_log1,
                                             mor0, mor1, dtb, acsb, csum);
    states_part_k<<<dim3(NCH, 4, 2), 256, 0, stream>>>(zxb, dtb, tail, acsb, csum,
                                                       mor0, mor1, spart);
    chunkscan_k<<<dim3(4, 2), 256, 0, stream>>>(csum, spart, prev);
    ychunk4_k<<<dim3(NCH, NH, 2), 1024, 0, stream>>>(zxb, tail, dtb, acsb, prev,
                                                     Dv0, Dv1, mor0, mor1, cat);

    zero2_k<<<dim3(224, 1), 256, 0, stream>>>(cat + (size_t)L_SEQ * 512, 0, 112 * 512);
    wsgemm_k<0, 512, 1, 2, 256><<<512, 512, 0, stream>>>(cat, wbufO, projb, nullptr, nullptr);

    lntr_k<<<507, 256, 0, stream>>>(projb, ln_g, ln_b, (float*)d_out);
}